// Round 3
// baseline (454.567 us; speedup 1.0000x reference)
//
#include <hip/hip_runtime.h>
#include <hip/hip_bf16.h>

typedef unsigned short u16;
using bf16_t = __hip_bfloat16;
typedef short short8 __attribute__((ext_vector_type(8)));
typedef float f32x4 __attribute__((ext_vector_type(4)));

__device__ __forceinline__ float b2f(u16 u) {
    return __uint_as_float((unsigned int)u << 16);
}
__device__ __forceinline__ u16 f2b(float f) {
    bf16_t h = __float2bfloat16(f);
    union { bf16_t h; u16 u; } cv; cv.h = h; return cv.u;
}
__device__ __forceinline__ float ldv(const void* p, size_t i, int f32) {
    return f32 ? ((const float*)p)[i] : b2f(((const u16*)p)[i]);
}
__device__ __forceinline__ uint4 pack8(float4 a, float4 b) {
    uint4 u;
    u.x = (unsigned)f2b(a.x) | ((unsigned)f2b(a.y) << 16);
    u.y = (unsigned)f2b(a.z) | ((unsigned)f2b(a.w) << 16);
    u.z = (unsigned)f2b(b.x) | ((unsigned)f2b(b.y) << 16);
    u.w = (unsigned)f2b(b.z) | ((unsigned)f2b(b.w) << 16);
    return u;
}
// XOR swizzle for stride-64(u16) LDS tiles: spreads the 16-row column reads
// across banks; bijective on k in [0,64); keeps 8-u16 groups contiguous.
__device__ __forceinline__ int swz(int n, int k) {
    return k ^ ((n & 7) << 3);
}

// ---------------------------------------------------------------------------
// Input-dtype detector (flag=1 -> fp32 inputs & fp32 output).
// ---------------------------------------------------------------------------
__global__ void detect_kernel(const void* __restrict__ x, int* __restrict__ flag)
{
    const int t = threadIdx.x;
    const u16 h = ((const u16*)x)[2 * t];
    const int e = (h >> 7) & 0xFF;
    const int plaus = (e >= 112 && e <= 133) ? 1 : 0;
    const unsigned long long m = __ballot(plaus);
    if (t == 0) flag[0] = (__popcll(m) < 32) ? 1 : 0;
}

// pe -> peb (bf16 always).
__global__ __launch_bounds__(256)
void pecvt_kernel(const void* __restrict__ pe, u16* __restrict__ peb,
                  const int* __restrict__ flagp)
{
    const size_t i = ((size_t)blockIdx.x * 256 + threadIdx.x) * 4;
    if (*flagp) {
        const float4 f = *reinterpret_cast<const float4*>((const float*)pe + i);
        ushort4 o; o.x = f2b(f.x); o.y = f2b(f.y); o.z = f2b(f.z); o.w = f2b(f.w);
        *reinterpret_cast<ushort4*>(peb + i) = o;
    } else {
        *reinterpret_cast<ushort4*>(peb + i) =
            *reinterpret_cast<const ushort4*>((const u16*)pe + i);
    }
}

// W[K x N] -> WT[N x K(=256)] bf16, LDS-tiled transpose.
__global__ __launch_bounds__(256)
void wtrans_kernel(const void* __restrict__ W, u16* __restrict__ WT, int N,
                   const int* __restrict__ flagp)
{
    const int f32 = *flagp;
    __shared__ float tile[32][33];
    const int tx = threadIdx.x & 31, ty = threadIdx.x >> 5;   // ty 0..7
    const int bx = blockIdx.x % (N >> 5);   // n tile
    const int by = blockIdx.x / (N >> 5);   // k tile
    #pragma unroll
    for (int r = 0; r < 4; ++r) {
        const int k = by * 32 + ty + r * 8;
        const int n = bx * 32 + tx;
        tile[ty + r * 8][tx] = ldv(W, (size_t)k * N + n, f32);
    }
    __syncthreads();
    #pragma unroll
    for (int r = 0; r < 4; ++r) {
        const int n2 = bx * 32 + ty + r * 8;
        const int k2 = by * 32 + tx;
        WT[(size_t)n2 * 256 + k2] = f2b(tile[tx][ty + r * 8]);
    }
}

// ---------------------------------------------------------------------------
// MFMA GEMM, BN=256 (final projection): out = A[rows x 256] @ B + bias.
// 128x256 block tile, BK=64, 4 waves as 2(m)x2(n); wave tile 64x128.
// ---------------------------------------------------------------------------
template<int MODE>
__global__ __launch_bounds__(256, 2)
void gemm256(const void* __restrict__ Aany, const u16* __restrict__ Abf,
             const u16* __restrict__ BT, u16* __restrict__ O0,
             const void* __restrict__ extra, const int* __restrict__ flagp)
{
    const int f32 = *flagp;
    __shared__ u16 As[128 * 72];     // [m][k], stride 72
    __shared__ u16 Bs[256 * 72];     // [n][k]

    const int tid  = threadIdx.x;
    const int row0 = blockIdx.x * 128;
    const int lane = tid & 63;
    const int wv   = tid >> 6;
    const int wm   = (wv & 1) * 64;          // wave row base
    const int wn   = (wv >> 1) * 128;        // wave col base
    const int l15  = lane & 15;
    const int lq   = lane >> 4;

    const int sr = tid >> 1;              // A staging row 0..127
    const int sk = (tid & 1) * 32;        // A staging k-half

    f32x4 acc[4][8] = {};

    for (int k0 = 0; k0 < 256; k0 += 64) {
        // A: row sr, 32 u16 at k0+sk.
        u16* al = &As[sr * 72 + sk];
        const size_t arow = (size_t)(row0 + sr) * 256 + k0 + sk;
        {
            const u16* ag = Abf + arow;
            #pragma unroll
            for (int j = 0; j < 4; ++j)
                *reinterpret_cast<uint4*>(al + j * 8) =
                    *reinterpret_cast<const uint4*>(ag + j * 8);
        }
        // B: row tid (all 256 n), 64 u16 at k0.
        {
            u16* bl = &Bs[tid * 72];
            const u16* bg = BT + (size_t)tid * 256 + k0;
            #pragma unroll
            for (int j = 0; j < 8; ++j)
                *reinterpret_cast<uint4*>(bl + j * 8) =
                    *reinterpret_cast<const uint4*>(bg + j * 8);
        }
        __syncthreads();
        #pragma unroll
        for (int ks = 0; ks < 64; ks += 32) {
            short8 av[4], bv[8];
            #pragma unroll
            for (int i = 0; i < 4; ++i)
                av[i] = *reinterpret_cast<const short8*>(
                    &As[(wm + i * 16 + l15) * 72 + ks + lq * 8]);
            #pragma unroll
            for (int j = 0; j < 8; ++j)
                bv[j] = *reinterpret_cast<const short8*>(
                    &Bs[(wn + j * 16 + l15) * 72 + ks + lq * 8]);
            #pragma unroll
            for (int i = 0; i < 4; ++i)
                #pragma unroll
                for (int j = 0; j < 8; ++j)
                    acc[i][j] = __builtin_amdgcn_mfma_f32_16x16x32_bf16(
                        av[i], bv[j], acc[i][j], 0, 0, 0);
        }
        __syncthreads();
    }

    // Store. C/D layout: row=(lane>>4)*4+reg, col=lane&15 (m89-verified).
    #pragma unroll
    for (int i = 0; i < 4; ++i) {
        #pragma unroll
        for (int j = 0; j < 8; ++j) {
            const int gcol = wn + j * 16 + l15;
            #pragma unroll
            for (int rg = 0; rg < 4; ++rg) {
                const int lr = wm + i * 16 + lq * 4 + rg;
                const size_t oi = (size_t)(row0 + lr) * 256 + gcol;
                const float o = acc[i][j][rg] + ldv(extra, gcol, f32);
                if (f32) ((float*)O0)[oi] = o;
                else     O0[oi] = f2b(o);
            }
        }
    }
}

// ---------------------------------------------------------------------------
// xfused: per 64-row chunk, x staged ONCE into 32 VGPRs (fp32->bf16), then
// three sequential 64x256 MFMA passes reusing the register copy of A:
//   pass q: acc = x@Wq           -> focus -> qy (bf16)
//   pass v: acc = x@Wkv[:,256:]  -> v global + VsT (LDS, from registers)
//   pass k: acc = x@Wkv[:,:256]  -> +peb, focus -> KsT (aliases Bs)
//           -> kvsum += KsT^T VsT per head via MFMA; ksum partials.
// 2 chunks per block (grid 512); kvsum/ksum accumulated in registers across
// chunks; atomics once at end, hashed over 2 slots (halved contention).
// Replaces q-gemm + v-gemm + fusedk: x read 1x instead of 3x, v never
// re-read for kvsum.
// LDS: As 9216 + Bs/KsT 32768 + VsT 32768 (+reduce arrays) ~= 78 KB ->
// 2 blocks/CU. Bs/KsT/VsT are stride-64 XOR-swizzled (bank-spread).
// ---------------------------------------------------------------------------
__global__ __launch_bounds__(256, 2)
void xfused_kernel(const void* __restrict__ x, const u16* __restrict__ WqT,
                   const u16* __restrict__ WkvT, const u16* __restrict__ peb,
                   const void* __restrict__ sp,
                   u16* __restrict__ qy, u16* __restrict__ v,
                   float* __restrict__ kvsm, float* __restrict__ ksm,
                   const int* __restrict__ flagp)
{
    const int f32 = *flagp;
    __shared__ u16 smem[4608 + 16384 + 16384];   // 74752 B
    __shared__ float red2[4][64];
    __shared__ float red6[4][64];
    __shared__ float ratio_s[64];
    __shared__ float sscr[256];
    u16* As  = smem;                  // [64][72]
    u16* Bs  = smem + 4608;           // [256][64] swizzled; aliased as KsT
    u16* KsT = Bs;
    u16* VsT = smem + 4608 + 16384;   // [256][64] swizzled

    const int tid  = threadIdx.x;
    const int lane = tid & 63;
    const int wv   = tid >> 6;        // 0..3
    const int l15  = lane & 15;
    const int lq   = lane >> 4;
    const int wn   = wv * 64;

    const int ar  = tid >> 2;         // x-slice row 0..63
    const int aco = (tid & 3) * 16;   // x-slice col base within 64-k window

    {
        const float p = ldv(sp, tid, f32);
        const float s = (p > 20.f) ? p : log1pf(expf(p));
        sscr[tid] = 1.0f / s;
    }

    f32x4 cc[2][4] = {};                 // kvsum accum (2 heads/wave)
    float ksp[4] = {0.f, 0.f, 0.f, 0.f}; // ksum accum

    const int b = blockIdx.x >> 5;       // batch (128 rows/block, 32 blk/batch)

    // GEMM pass: acc = x(regs) @ BT, 4 K-steps.
    auto run_gemm = [&](const u16* BT, const uint4 (&xr)[4][2],
                        f32x4 (&acc)[4][4]) {
        for (int k0i = 0; k0i < 4; ++k0i) {
            *reinterpret_cast<uint4*>(&As[ar * 72 + aco])     = xr[k0i][0];
            *reinterpret_cast<uint4*>(&As[ar * 72 + aco + 8]) = xr[k0i][1];
            {
                const u16* bg = BT + (size_t)tid * 256 + k0i * 64;
                u16* bl = &Bs[tid * 64];
                #pragma unroll
                for (int j = 0; j < 8; ++j)
                    *reinterpret_cast<uint4*>(&bl[swz(tid, j * 8)]) =
                        *reinterpret_cast<const uint4*>(bg + j * 8);
            }
            __syncthreads();
            #pragma unroll
            for (int ks = 0; ks < 64; ks += 32) {
                short8 av[4], bvv[4];
                #pragma unroll
                for (int i = 0; i < 4; ++i)
                    av[i] = *reinterpret_cast<const short8*>(
                        &As[(i * 16 + l15) * 72 + ks + lq * 8]);
                #pragma unroll
                for (int j = 0; j < 4; ++j) {
                    const int bn = wn + j * 16 + l15;
                    bvv[j] = *reinterpret_cast<const short8*>(
                        &Bs[bn * 64 + swz(bn, ks + lq * 8)]);
                }
                #pragma unroll
                for (int i = 0; i < 4; ++i)
                    #pragma unroll
                    for (int j = 0; j < 4; ++j)
                        acc[i][j] = __builtin_amdgcn_mfma_f32_16x16x32_bf16(
                            av[i], bvv[j], acc[i][j], 0, 0, 0);
            }
            __syncthreads();
        }
    };

    // focus: normalize acc in place (xv=(relu+eps)/softplus), ratio_s set.
    auto focus_acc = [&](f32x4 (&acc)[4][4], int addpe, int nb) {
        #pragma unroll
        for (int i = 0; i < 4; ++i) {
            #pragma unroll
            for (int rg = 0; rg < 4; ++rg) {
                const int lrow = i * 16 + lq * 4 + rg;
                float s2 = 0.f, s6 = 0.f;
                #pragma unroll
                for (int j = 0; j < 4; ++j) {
                    const int col = wn + j * 16 + l15;
                    float t = acc[i][j][rg];
                    if (addpe) t += b2f(peb[(size_t)(nb + lrow) * 256 + col]);
                    const float xv = (fmaxf(t, 0.f) + 1e-6f) * sscr[col];
                    acc[i][j][rg] = xv;
                    const float x2 = xv * xv;
                    s2 += x2;
                    s6 += x2 * x2 * x2;
                }
                #pragma unroll
                for (int off = 1; off < 16; off <<= 1) {
                    s2 += __shfl_xor(s2, off);
                    s6 += __shfl_xor(s6, off);
                }
                if (l15 == 0) { red2[wv][lrow] = s2; red6[wv][lrow] = s6; }
            }
        }
        __syncthreads();
        if (tid < 64) {
            const float s2t = red2[0][tid] + red2[1][tid] + red2[2][tid] + red2[3][tid];
            const float s6t = red6[0][tid] + red6[1][tid] + red6[2][tid] + red6[3][tid];
            ratio_s[tid] = sqrtf(s2t / s6t);
        }
        __syncthreads();
    };

    for (int c = 0; c < 2; ++c) {
        const int row0 = blockIdx.x * 128 + c * 64;
        const int nb   = row0 & 4095;

        // ---- Stage x slice into registers (read x ONCE). ------------------
        uint4 xr[4][2];
        const size_t xbase = (size_t)(row0 + ar) * 256 + aco;
        if (f32) {
            const float* ag = (const float*)x + xbase;
            #pragma unroll
            for (int k0i = 0; k0i < 4; ++k0i)
                #pragma unroll
                for (int h = 0; h < 2; ++h) {
                    const float4 f0 = *reinterpret_cast<const float4*>(ag + k0i * 64 + h * 8);
                    const float4 f1 = *reinterpret_cast<const float4*>(ag + k0i * 64 + h * 8 + 4);
                    xr[k0i][h] = pack8(f0, f1);
                }
        } else {
            const u16* ag = (const u16*)x + xbase;
            #pragma unroll
            for (int k0i = 0; k0i < 4; ++k0i)
                #pragma unroll
                for (int h = 0; h < 2; ++h)
                    xr[k0i][h] = *reinterpret_cast<const uint4*>(ag + k0i * 64 + h * 8);
        }

        f32x4 acc[4][4];

        // ---- pass q: qy = focus(x @ Wq) -----------------------------------
        #pragma unroll
        for (int i = 0; i < 4; ++i)
            #pragma unroll
            for (int j = 0; j < 4; ++j) acc[i][j] = f32x4{0.f, 0.f, 0.f, 0.f};
        run_gemm(WqT, xr, acc);
        focus_acc(acc, 0, nb);
        #pragma unroll
        for (int i = 0; i < 4; ++i)
            #pragma unroll
            for (int rg = 0; rg < 4; ++rg) {
                const int lrow = i * 16 + lq * 4 + rg;
                const float rt = ratio_s[lrow];
                #pragma unroll
                for (int j = 0; j < 4; ++j) {
                    const float xv = acc[i][j][rg];
                    qy[(size_t)(row0 + lrow) * 256 + wn + j * 16 + l15] =
                        f2b(xv * xv * xv * rt);
                }
            }

        // ---- pass v: v = x @ Wkv[:,256:]; VsT from registers --------------
        #pragma unroll
        for (int i = 0; i < 4; ++i)
            #pragma unroll
            for (int j = 0; j < 4; ++j) acc[i][j] = f32x4{0.f, 0.f, 0.f, 0.f};
        run_gemm(WkvT + (size_t)256 * 256, xr, acc);
        #pragma unroll
        for (int i = 0; i < 4; ++i)
            #pragma unroll
            for (int rg = 0; rg < 4; ++rg) {
                const int lrow = i * 16 + lq * 4 + rg;
                #pragma unroll
                for (int j = 0; j < 4; ++j) {
                    const int e = wn + j * 16 + l15;
                    const u16 hv = f2b(acc[i][j][rg]);
                    v[(size_t)(row0 + lrow) * 256 + e] = hv;
                    VsT[e * 64 + swz(e, lrow)] = hv;
                }
            }

        // ---- pass k: k = focus(x @ Wkv[:,:256] + pe) -> KsT ---------------
        #pragma unroll
        for (int i = 0; i < 4; ++i)
            #pragma unroll
            for (int j = 0; j < 4; ++j) acc[i][j] = f32x4{0.f, 0.f, 0.f, 0.f};
        run_gemm(WkvT, xr, acc);
        focus_acc(acc, 1, nb);
        {
            float kscol[4] = {0.f, 0.f, 0.f, 0.f};
            #pragma unroll
            for (int i = 0; i < 4; ++i)
                #pragma unroll
                for (int rg = 0; rg < 4; ++rg) {
                    const int lrow = i * 16 + lq * 4 + rg;
                    const float rt = ratio_s[lrow];
                    #pragma unroll
                    for (int j = 0; j < 4; ++j) {
                        const float xv = acc[i][j][rg];
                        const float kf = xv * xv * xv * rt;
                        const int d = wn + j * 16 + l15;
                        KsT[d * 64 + swz(d, lrow)] = f2b(kf);
                        kscol[j] += kf;
                    }
                }
            #pragma unroll
            for (int j = 0; j < 4; ++j) {
                float kp = kscol[j];
                kp += __shfl_xor(kp, 16);
                kp += __shfl_xor(kp, 32);
                ksp[j] += kp;
            }
        }
        __syncthreads();

        // ---- phase 3: kvsum += KsT^T VsT per head via MFMA ----------------
        #pragma unroll
        for (int hh = 0; hh < 2; ++hh) {
            const int cb = (wv * 2 + hh) * 32;
            const int da = cb + l15, dbx = cb + 16 + l15;
            #pragma unroll
            for (int kk = 0; kk < 64; kk += 32) {
                const int ko = kk + lq * 8;
                const short8 a0 = *reinterpret_cast<const short8*>(
                    &KsT[da * 64 + swz(da, ko)]);
                const short8 a1 = *reinterpret_cast<const short8*>(
                    &KsT[dbx * 64 + swz(dbx, ko)]);
                const short8 b0 = *reinterpret_cast<const short8*>(
                    &VsT[da * 64 + swz(da, ko)]);
                const short8 b1 = *reinterpret_cast<const short8*>(
                    &VsT[dbx * 64 + swz(dbx, ko)]);
                cc[hh][0] = __builtin_amdgcn_mfma_f32_16x16x32_bf16(a0, b0, cc[hh][0], 0, 0, 0);
                cc[hh][1] = __builtin_amdgcn_mfma_f32_16x16x32_bf16(a0, b1, cc[hh][1], 0, 0, 0);
                cc[hh][2] = __builtin_amdgcn_mfma_f32_16x16x32_bf16(a1, b0, cc[hh][2], 0, 0, 0);
                cc[hh][3] = __builtin_amdgcn_mfma_f32_16x16x32_bf16(a1, b1, cc[hh][3], 0, 0, 0);
            }
        }
        __syncthreads();
    }

    // ---- Atomics once per block (slot-hashed: halves contention). ---------
    const int slot = blockIdx.x & 1;
    float* ksb = ksm + (size_t)(slot * 16 + b) * 256;
    #pragma unroll
    for (int j = 0; j < 4; ++j)
        if (lane < 16)
            atomicAdd(&ksb[wn + j * 16 + lane], ksp[j]);
    #pragma unroll
    for (int hh = 0; hh < 2; ++hh) {
        const int h = wv * 2 + hh;
        float* base = kvsm + ((size_t)(slot * 16 + b) * 8 + h) * 1024;
        #pragma unroll
        for (int rg = 0; rg < 4; ++rg) {
            const int d0 = lq * 4 + rg;
            atomicAdd(&base[(size_t)d0 * 32 + l15],             cc[hh][0][rg]);
            atomicAdd(&base[(size_t)d0 * 32 + 16 + l15],        cc[hh][1][rg]);
            atomicAdd(&base[(size_t)(d0 + 16) * 32 + l15],      cc[hh][2][rg]);
            atomicAdd(&base[(size_t)(d0 + 16) * 32 + 16 + l15], cc[hh][3][rg]);
        }
    }
}

// ---------------------------------------------------------------------------
// attn IN-PLACE on qy (sums the 2 kvsum/ksum slots).
// ---------------------------------------------------------------------------
__global__ __launch_bounds__(256)
void attn_kernel(u16* qy, const float* __restrict__ kvsum,
                 const float* __restrict__ ksum)
{
    __shared__ float kvs[8][32][32];
    __shared__ float km[8][32];
    __shared__ float qs[16][256];
    const int tid = threadIdx.x;
    const int b   = blockIdx.x >> 8;
    const int n0  = (blockIdx.x & 255) * 16;
    const float inv_n = 1.0f / 4096.0f;
    for (int i = tid; i < 8 * 32 * 32; i += 256)
        (&kvs[0][0][0])[i] = (kvsum[(size_t)b * 8192 + i] +
                              kvsum[(size_t)(16 + b) * 8192 + i]) * inv_n;
    (&km[0][0])[tid] = (ksum[(size_t)b * 256 + tid] +
                        ksum[(size_t)(16 + b) * 256 + tid]) * inv_n;
    u16* qb = qy + ((size_t)b * 4096 + n0) * 256;
    #pragma unroll
    for (int t = 0; t < 16; ++t)
        qs[t][tid] = b2f(qb[(size_t)t * 256 + tid]);
    __syncthreads();
    const int h = tid >> 5, e = tid & 31;
    for (int t = 0; t < 16; ++t) {
        float acc = 0.f, zd = 0.f;
        #pragma unroll
        for (int d = 0; d < 32; ++d) {
            const float qv = qs[t][h * 32 + d];
            acc = fmaf(qv, kvs[h][d][e], acc);
            zd  = fmaf(qv, km[h][d], zd);
        }
        qb[(size_t)t * 256 + tid] = f2b(acc / (zd + 1e-6f));
    }
}

// ---------------------------------------------------------------------------
// Depthwise 5x5 conv: LDS-staged 12x12x256 halo tile (vectorized uint4
// staging), thread=channel, register-resident sliding 5x12 window, 8x8
// outputs/thread, += into y with bias.
// ---------------------------------------------------------------------------
__global__ __launch_bounds__(256, 2)
void conv_add_kernel(const u16* __restrict__ v, const void* __restrict__ w,
                     const void* __restrict__ bias, u16* __restrict__ y,
                     const int* __restrict__ flagp)
{
    const int f32 = *flagp;
    __shared__ u16 vt[144 * 256];   // [py*12+px][ch], 73728 B
    __shared__ float wl[800];
    __shared__ float bl[32];
    const int tid = threadIdx.x;
    for (int i = tid; i < 800; i += 256) wl[i] = ldv(w, i, f32);
    if (tid < 32) bl[tid] = ldv(bias, tid, f32);

    const int bb = blockIdx.x >> 6;
    const int ty = (blockIdx.x >> 3) & 7;
    const int tx = blockIdx.x & 7;
    const int y0 = ty * 8, x0 = tx * 8;
    const u16* vb = v + (size_t)bb * 4096 * 256;

    #pragma unroll
    for (int it = 0; it < 18; ++it) {
        const int idx = it * 256 + tid;       // 0..4607
        const int px  = idx >> 5;             // 0..143
        const int c8  = (idx & 31) * 8;
        const int py  = px / 12, pxx = px - py * 12;
        const int yy = y0 + py - 2, xx = x0 + pxx - 2;
        uint4 val = {0u, 0u, 0u, 0u};
        if (yy >= 0 && yy < 64 && xx >= 0 && xx < 64)
            val = *reinterpret_cast<const uint4*>(
                vb + (size_t)((yy << 6) + xx) * 256 + c8);
        *reinterpret_cast<uint4*>(&vt[px * 256 + c8]) = val;
    }
    __syncthreads();

    const int c  = tid;            // channel
    const int dc = c & 31;
    float wreg[25];
    #pragma unroll
    for (int i = 0; i < 25; ++i) wreg[i] = wl[dc * 25 + i];
    const float bv = bl[dc];

    float win[5][12];
    #pragma unroll
    for (int r = 0; r < 5; ++r)
        #pragma unroll
        for (int cc = 0; cc < 12; ++cc)
            win[r][cc] = b2f(vt[(r * 12 + cc) * 256 + c]);

    u16* yb = y + ((size_t)bb * 4096 + (size_t)y0 * 64 + x0) * 256 + c;
    #pragma unroll
    for (int oy = 0; oy < 8; ++oy) {
        if (oy) {
            #pragma unroll
            for (int r = 0; r < 4; ++r)
                #pragma unroll
                for (int cc = 0; cc < 12; ++cc) win[r][cc] = win[r + 1][cc];
            #pragma unroll
            for (int cc = 0; cc < 12; ++cc)
                win[4][cc] = b2f(vt[((oy + 4) * 12 + cc) * 256 + c]);
        }
        #pragma unroll
        for (int ox = 0; ox < 8; ++ox) {
            float s = 0.f;
            #pragma unroll
            for (int ky = 0; ky < 5; ++ky)
                #pragma unroll
                for (int kx = 0; kx < 5; ++kx)
                    s = fmaf(win[ky][ox + kx], wreg[ky * 5 + kx], s);
            u16* yp = yb + (size_t)(oy * 64 + ox) * 256;
            *yp = f2b(b2f(*yp) + s + bv);
        }
    }
}

// ---------------------------------------------------------------------------
extern "C" void kernel_launch(void* const* d_in, const int* in_sizes, int n_in,
                              void* d_out, int out_size, void* d_ws, size_t ws_size,
                              hipStream_t stream)
{
    (void)in_sizes; (void)n_in; (void)out_size; (void)ws_size;
    const void* x   = d_in[0];
    const void* Wq  = d_in[1];
    const void* Wkv = d_in[2];
    const void* Wp  = d_in[3];
    const void* bp  = d_in[4];
    const void* sp  = d_in[5];
    const void* pe  = d_in[6];
    const void* dw  = d_in[7];
    const void* db  = d_in[8];

    // ws layout (~37 MB):
    // [flag 64B][kvsm 1M (2 slots)][ksm 32K (2 slots)][WqT 128K][WkvT 256K]
    // [WpT 128K][peb 2M][qy 33.5M]
    int*   flag = (int*)d_ws;
    float* kvsm = (float*)((char*)d_ws + 64);
    float* ksm  = kvsm + 262144;
    u16*   WqT  = (u16*)(ksm + 8192);
    u16*   WkvT = WqT + 65536;
    u16*   WpT  = WkvT + 131072;
    u16*   peb  = WpT + 65536;
    u16*   qy   = peb + 1048576;
    // v (bf16, 33.5 MB) parked at the START of d_out (dead before the final
    // GEMM overwrites d_out).
    u16*   v    = (u16*)d_out;

    hipMemsetAsync(kvsm, 0, (262144 + 8192) * sizeof(float), stream);
    detect_kernel<<<1, 64, 0, stream>>>(x, flag);
    pecvt_kernel<<<1024, 256, 0, stream>>>(pe, peb, flag);
    wtrans_kernel<<<64, 256, 0, stream>>>(Wq, WqT, 256, flag);
    wtrans_kernel<<<128, 256, 0, stream>>>(Wkv, WkvT, 512, flag);
    wtrans_kernel<<<64, 256, 0, stream>>>(Wp, WpT, 256, flag);

    // q, v, k(+kvsum/ksum) in ONE pass over x.
    xfused_kernel<<<512, 256, 0, stream>>>(x, WqT, WkvT, peb, sp,
                                           qy, v, kvsm, ksm, flag);

    attn_kernel<<<4096, 256, 0, stream>>>(qy, kvsm, ksm);
    conv_add_kernel<<<1024, 256, 0, stream>>>(v, dw, db, qy, flag);
    hipLaunchKernelGGL((gemm256<2>), dim3(512), dim3(256), 0, stream,
                       (const void*)nullptr, qy, WpT, (u16*)d_out, bp, flag);
}

// Round 4
// 370.286 us; speedup vs baseline: 1.2276x; 1.2276x over previous
//
#include <hip/hip_runtime.h>
#include <hip/hip_bf16.h>

typedef unsigned short u16;
using bf16_t = __hip_bfloat16;
typedef short short8 __attribute__((ext_vector_type(8)));
typedef float f32x4 __attribute__((ext_vector_type(4)));

__device__ __forceinline__ float b2f(u16 u) {
    return __uint_as_float((unsigned int)u << 16);
}
__device__ __forceinline__ u16 f2b(float f) {
    bf16_t h = __float2bfloat16(f);
    union { bf16_t h; u16 u; } cv; cv.h = h; return cv.u;
}
__device__ __forceinline__ float ldv(const void* p, size_t i, int f32) {
    return f32 ? ((const float*)p)[i] : b2f(((const u16*)p)[i]);
}
__device__ __forceinline__ uint4 pack8(float4 a, float4 b) {
    uint4 u;
    u.x = (unsigned)f2b(a.x) | ((unsigned)f2b(a.y) << 16);
    u.y = (unsigned)f2b(a.z) | ((unsigned)f2b(a.w) << 16);
    u.z = (unsigned)f2b(b.x) | ((unsigned)f2b(b.y) << 16);
    u.w = (unsigned)f2b(b.z) | ((unsigned)f2b(b.w) << 16);
    return u;
}
// XOR swizzle for stride-64(u16) LDS tiles: element (n,k) lives at
// n*64 + (k ^ ((n&7)<<3)). Bijective within each row; 16B blocks preserved.
__device__ __forceinline__ int swz(int n, int k) {
    return k ^ ((n & 7) << 3);
}
// Async global->LDS DMA, 16B per lane. LDS dest must be wave-uniform base;
// HW writes lane i at base + i*16B. Global src is per-lane (pre-swizzled).
__device__ __forceinline__ void gl16(const u16* g, u16* l) {
    __builtin_amdgcn_global_load_lds(
        (const __attribute__((address_space(1))) unsigned int*)g,
        (__attribute__((address_space(3))) unsigned int*)l, 16, 0, 0);
}

// ---------------------------------------------------------------------------
// Input-dtype detector (flag=1 -> fp32 inputs & fp32 output).
// ---------------------------------------------------------------------------
__global__ void detect_kernel(const void* __restrict__ x, int* __restrict__ flag)
{
    const int t = threadIdx.x;
    const u16 h = ((const u16*)x)[2 * t];
    const int e = (h >> 7) & 0xFF;
    const int plaus = (e >= 112 && e <= 133) ? 1 : 0;
    const unsigned long long m = __ballot(plaus);
    if (t == 0) flag[0] = (__popcll(m) < 32) ? 1 : 0;
}

// pe -> peb (bf16 always).
__global__ __launch_bounds__(256)
void pecvt_kernel(const void* __restrict__ pe, u16* __restrict__ peb,
                  const int* __restrict__ flagp)
{
    const size_t i = ((size_t)blockIdx.x * 256 + threadIdx.x) * 4;
    if (*flagp) {
        const float4 f = *reinterpret_cast<const float4*>((const float*)pe + i);
        ushort4 o; o.x = f2b(f.x); o.y = f2b(f.y); o.z = f2b(f.z); o.w = f2b(f.w);
        *reinterpret_cast<ushort4*>(peb + i) = o;
    } else {
        *reinterpret_cast<ushort4*>(peb + i) =
            *reinterpret_cast<const ushort4*>((const u16*)pe + i);
    }
}

// W[K x N] -> WT[N x K(=256)] bf16, LDS-tiled transpose.
__global__ __launch_bounds__(256)
void wtrans_kernel(const void* __restrict__ W, u16* __restrict__ WT, int N,
                   const int* __restrict__ flagp)
{
    const int f32 = *flagp;
    __shared__ float tile[32][33];
    const int tx = threadIdx.x & 31, ty = threadIdx.x >> 5;   // ty 0..7
    const int bx = blockIdx.x % (N >> 5);   // n tile
    const int by = blockIdx.x / (N >> 5);   // k tile
    #pragma unroll
    for (int r = 0; r < 4; ++r) {
        const int k = by * 32 + ty + r * 8;
        const int n = bx * 32 + tx;
        tile[ty + r * 8][tx] = ldv(W, (size_t)k * N + n, f32);
    }
    __syncthreads();
    #pragma unroll
    for (int r = 0; r < 4; ++r) {
        const int n2 = bx * 32 + ty + r * 8;
        const int k2 = by * 32 + tx;
        WT[(size_t)n2 * 256 + k2] = f2b(tile[tx][ty + r * 8]);
    }
}

// ---------------------------------------------------------------------------
// MFMA GEMM, BN=256: O[rows x 256] = A[rows x 256] @ B. 128x256 block tile,
// BK=64, 4 waves 2(m)x2(n), wave tile 64x128 (acc[4][8]).
// Staging: B always via global_load_lds (16B/lane DMA) into linear stride-64
// LDS with XOR-pre-swizzled global source; reads use the same XOR ->
// conflict-free ds_read_b128 and zero staging VALU. A likewise when bf16
// (MODE 2, or flag=0); fp32 A converts in VGPRs and writes swizzled.
// MODE 0: O0(bf16) = A@B                      (v-gemm)
// MODE 2: out = A@B + bias; fp32/bf16 store   (A = qy bf16)
// MODE 3: O0(bf16) = focus(A@B)               (q-gemm, focus fused)
// ---------------------------------------------------------------------------
template<int MODE>
__global__ __launch_bounds__(256, 2)
void gemm256(const void* __restrict__ Aany, const u16* __restrict__ Abf,
             const u16* __restrict__ BT, u16* __restrict__ O0,
             const void* __restrict__ extra, const int* __restrict__ flagp)
{
    const int f32 = *flagp;
    __shared__ u16 As[128 * 64];     // linear, swizzled content
    __shared__ u16 Bs[256 * 64];
    __shared__ float red2[2][128];
    __shared__ float red6[2][128];
    __shared__ float ratio_s[128];
    __shared__ float sscr[256];

    const int tid  = threadIdx.x;
    const int row0 = blockIdx.x * 128;
    const int lane = tid & 63;
    const int wv   = tid >> 6;
    const int wvu  = __builtin_amdgcn_readfirstlane(wv);
    const int wm   = (wv & 1) * 64;          // wave row base
    const int wn   = (wv >> 1) * 128;        // wave col base
    const int l15  = lane & 15;
    const int lq   = lane >> 4;
    const int lr8  = lane >> 3;              // staging: row within 8-group
    const int lc8  = (lane & 7) * 8;         // staging: col (u16) within row

    if (MODE == 3) {
        const float p = ldv(extra, tid, f32);
        const float s = (p > 20.f) ? p : log1pf(expf(p));
        sscr[tid] = 1.0f / s;
    }

    f32x4 acc[4][8] = {};

    for (int k0 = 0; k0 < 256; k0 += 64) {
        // ---- B stage: wave w rows [w*64, w*64+64), 8 DMA instrs. ----------
        #pragma unroll
        for (int it = 0; it < 8; ++it) {
            const int r = wvu * 64 + it * 8 + lr8;
            gl16(BT + (size_t)r * 256 + k0 + swz(r, lc8),
                 &Bs[(wvu * 64 + it * 8) * 64]);
        }
        // ---- A stage ------------------------------------------------------
        if (MODE == 2 || !f32) {
            const u16* Ab = (MODE == 2) ? Abf : (const u16*)Aany;
            #pragma unroll
            for (int it = 0; it < 4; ++it) {
                const int r = wvu * 32 + it * 8 + lr8;
                gl16(Ab + (size_t)(row0 + r) * 256 + k0 + swz(r, lc8),
                     &As[(wvu * 32 + it * 8) * 64]);
            }
        } else {
            const int sr = tid >> 1;              // row 0..127
            const int sk = (tid & 1) * 32;        // k-half
            const float* ag = (const float*)Aany +
                              (size_t)(row0 + sr) * 256 + k0 + sk;
            #pragma unroll
            for (int j = 0; j < 4; ++j) {
                const float4 f0 = *reinterpret_cast<const float4*>(ag + j * 8);
                const float4 f1 = *reinterpret_cast<const float4*>(ag + j * 8 + 4);
                *reinterpret_cast<uint4*>(
                    &As[sr * 64 + swz(sr, sk + j * 8)]) = pack8(f0, f1);
            }
        }
        __syncthreads();
        #pragma unroll
        for (int ks = 0; ks < 64; ks += 32) {
            const int ko = ks + lq * 8;
            short8 av[4], bv[8];
            #pragma unroll
            for (int i = 0; i < 4; ++i) {
                const int m = wm + i * 16 + l15;
                av[i] = *reinterpret_cast<const short8*>(&As[m * 64 + swz(m, ko)]);
            }
            #pragma unroll
            for (int j = 0; j < 8; ++j) {
                const int n = wn + j * 16 + l15;
                bv[j] = *reinterpret_cast<const short8*>(&Bs[n * 64 + swz(n, ko)]);
            }
            #pragma unroll
            for (int i = 0; i < 4; ++i)
                #pragma unroll
                for (int j = 0; j < 8; ++j)
                    acc[i][j] = __builtin_amdgcn_mfma_f32_16x16x32_bf16(
                        av[i], bv[j], acc[i][j], 0, 0, 0);
        }
        __syncthreads();
    }

    if (MODE == 3) {
        // focus: xv=(relu+eps)/softplus; per-row s2=sum xv^2, s6=sum xv^6.
        #pragma unroll
        for (int i = 0; i < 4; ++i) {
            #pragma unroll
            for (int rg = 0; rg < 4; ++rg) {
                const int lr = wm + i * 16 + lq * 4 + rg;   // local row 0..127
                float s2 = 0.f, s6 = 0.f;
                #pragma unroll
                for (int j = 0; j < 8; ++j) {
                    const int col = wn + j * 16 + l15;
                    const float xv =
                        (fmaxf(acc[i][j][rg], 0.f) + 1e-6f) * sscr[col];
                    acc[i][j][rg] = xv;
                    const float x2 = xv * xv;
                    s2 += x2;
                    s6 += x2 * x2 * x2;
                }
                #pragma unroll
                for (int off = 1; off < 16; off <<= 1) {
                    s2 += __shfl_xor(s2, off);
                    s6 += __shfl_xor(s6, off);
                }
                if (l15 == 0) { red2[wv >> 1][lr] = s2; red6[wv >> 1][lr] = s6; }
            }
        }
        __syncthreads();
        if (tid < 128)
            ratio_s[tid] = sqrtf((red2[0][tid] + red2[1][tid]) /
                                 (red6[0][tid] + red6[1][tid]));
        __syncthreads();
    }

    // Store. C/D layout: row=(lane>>4)*4+reg, col=lane&15 (m89-verified).
    #pragma unroll
    for (int i = 0; i < 4; ++i) {
        #pragma unroll
        for (int j = 0; j < 8; ++j) {
            const int gcol = wn + j * 16 + l15;
            #pragma unroll
            for (int rg = 0; rg < 4; ++rg) {
                const int lr = wm + i * 16 + lq * 4 + rg;
                const size_t oi = (size_t)(row0 + lr) * 256 + gcol;
                const float a = acc[i][j][rg];
                if (MODE == 0) {
                    O0[oi] = f2b(a);
                } else if (MODE == 3) {
                    O0[oi] = f2b(a * a * a * ratio_s[lr]);
                } else {
                    const float o = a + ldv(extra, gcol, f32);
                    if (f32) ((float*)O0)[oi] = o;
                    else     O0[oi] = f2b(o);
                }
            }
        }
    }
}

// ---------------------------------------------------------------------------
// Fused k-path: k = x @ Wkv[:, :256] + pe -> focus -> kvsum/ksum atomics.
// Round-2 structure (2 x 64-row chunks/block, register kvsum accum, atomics
// once at end) + global_load_lds B staging + swizzled KsT/VsT (round-3
// verified) + 2-slot atomic hashing.
// ---------------------------------------------------------------------------
__global__ __launch_bounds__(256, 2)
void fusedk_kernel(const void* __restrict__ x, const u16* __restrict__ WkvT,
                   const u16* __restrict__ peb, const u16* __restrict__ v,
                   const void* __restrict__ sp,
                   float* __restrict__ kvsm, float* __restrict__ ksm,
                   const int* __restrict__ flagp)
{
    const int f32 = *flagp;
    __shared__ u16 As[64 * 64];
    __shared__ u16 Bs[256 * 64];     // aliased as KsT after GEMM
    __shared__ u16 VsT[256 * 64];
    __shared__ float red2[4][64];
    __shared__ float red6[4][64];
    __shared__ float ratio_s[64];
    __shared__ float sscr[256];
    u16* KsT = Bs;

    const int tid  = threadIdx.x;
    const int lane = tid & 63;
    const int wv   = tid >> 6;           // 0..3
    const int wvu  = __builtin_amdgcn_readfirstlane(wv);
    const int l15  = lane & 15;
    const int lq   = lane >> 4;
    const int wn   = wv * 64;
    const int lr8  = lane >> 3;
    const int lc8  = (lane & 7) * 8;

    {
        const float p = ldv(sp, tid, f32);
        const float s = (p > 20.f) ? p : log1pf(expf(p));
        sscr[tid] = 1.0f / s;
    }

    f32x4 cc[2][4] = {};                 // kvsum accum (2 heads/wave)
    float ksp[4] = {0.f, 0.f, 0.f, 0.f}; // ksum accum

    const int b   = blockIdx.x >> 5;     // batch (128 rows/block)
    const int vr  = lane;                // V staging row
    const int veb = wv * 64;             // V staging col base

    for (int c = 0; c < 2; ++c) {
        const int row0 = blockIdx.x * 128 + c * 64;
        const int nb   = row0 & 4095;

        // ---- Phase 1: GEMM (64x256, BK=64). -------------------------------
        f32x4 acc[4][4] = {};
        for (int k0 = 0; k0 < 256; k0 += 64) {
            #pragma unroll
            for (int it = 0; it < 8; ++it) {
                const int r = wvu * 64 + it * 8 + lr8;
                gl16(WkvT + (size_t)r * 256 + k0 + swz(r, lc8),
                     &Bs[(wvu * 64 + it * 8) * 64]);
            }
            if (!f32) {
                #pragma unroll
                for (int it = 0; it < 2; ++it) {
                    const int r = wvu * 16 + it * 8 + lr8;
                    gl16((const u16*)x + (size_t)(row0 + r) * 256 + k0 + swz(r, lc8),
                         &As[(wvu * 16 + it * 8) * 64]);
                }
            } else {
                const int ar = tid >> 2, ak = (tid & 3) * 16;
                const float* ag = (const float*)x +
                                  (size_t)(row0 + ar) * 256 + k0 + ak;
                #pragma unroll
                for (int j = 0; j < 2; ++j) {
                    const float4 f0 = *reinterpret_cast<const float4*>(ag + j * 8);
                    const float4 f1 = *reinterpret_cast<const float4*>(ag + j * 8 + 4);
                    *reinterpret_cast<uint4*>(
                        &As[ar * 64 + swz(ar, ak + j * 8)]) = pack8(f0, f1);
                }
            }
            __syncthreads();
            #pragma unroll
            for (int ks = 0; ks < 64; ks += 32) {
                const int ko = ks + lq * 8;
                short8 av[4], bvv[4];
                #pragma unroll
                for (int i = 0; i < 4; ++i) {
                    const int m = i * 16 + l15;
                    av[i] = *reinterpret_cast<const short8*>(&As[m * 64 + swz(m, ko)]);
                }
                #pragma unroll
                for (int j = 0; j < 4; ++j) {
                    const int n = wn + j * 16 + l15;
                    bvv[j] = *reinterpret_cast<const short8*>(&Bs[n * 64 + swz(n, ko)]);
                }
                #pragma unroll
                for (int i = 0; i < 4; ++i)
                    #pragma unroll
                    for (int j = 0; j < 4; ++j)
                        acc[i][j] = __builtin_amdgcn_mfma_f32_16x16x32_bf16(
                            av[i], bvv[j], acc[i][j], 0, 0, 0);
            }
            __syncthreads();
        }

        // ---- Phase 2a: +peb, normalize, s2/s6 reduce ----------------------
        #pragma unroll
        for (int i = 0; i < 4; ++i) {
            #pragma unroll
            for (int rg = 0; rg < 4; ++rg) {
                const int lrow = i * 16 + lq * 4 + rg;
                float s2 = 0.f, s6 = 0.f;
                #pragma unroll
                for (int j = 0; j < 4; ++j) {
                    const int col = wn + j * 16 + l15;
                    const float t = acc[i][j][rg] +
                        b2f(peb[(size_t)(nb + lrow) * 256 + col]);
                    const float xv = (fmaxf(t, 0.f) + 1e-6f) * sscr[col];
                    acc[i][j][rg] = xv;
                    const float x2 = xv * xv;
                    s2 += x2;
                    s6 += x2 * x2 * x2;
                }
                #pragma unroll
                for (int off = 1; off < 16; off <<= 1) {
                    s2 += __shfl_xor(s2, off);
                    s6 += __shfl_xor(s6, off);
                }
                if (l15 == 0) { red2[wv][lrow] = s2; red6[wv][lrow] = s6; }
            }
        }
        __syncthreads();
        if (tid < 64) {
            const float s2t = red2[0][tid] + red2[1][tid] + red2[2][tid] + red2[3][tid];
            const float s6t = red6[0][tid] + red6[1][tid] + red6[2][tid] + red6[3][tid];
            ratio_s[tid] = sqrtf(s2t / s6t);
        }
        __syncthreads();

        // ---- Phase 2b: finalize k -> KsT[d][r] (swz); ksum partials. ------
        {
            float kscol[4] = {0.f, 0.f, 0.f, 0.f};
            #pragma unroll
            for (int i = 0; i < 4; ++i)
                #pragma unroll
                for (int rg = 0; rg < 4; ++rg) {
                    const int lrow = i * 16 + lq * 4 + rg;
                    const float rt = ratio_s[lrow];
                    #pragma unroll
                    for (int j = 0; j < 4; ++j) {
                        const float xv = acc[i][j][rg];
                        const float kf = xv * xv * xv * rt;
                        const int d = wn + j * 16 + l15;
                        KsT[d * 64 + swz(d, lrow)] = f2b(kf);
                        kscol[j] += kf;
                    }
                }
            #pragma unroll
            for (int j = 0; j < 4; ++j) {
                float kp = kscol[j];
                kp += __shfl_xor(kp, 16);
                kp += __shfl_xor(kp, 32);
                ksp[j] += kp;
            }
        }

        // ---- Stage V transposed: VsT[e][r] (swz). -------------------------
        {
            const u16* vg = v + (size_t)(row0 + vr) * 256 + veb;
            uint4 t0[8];
            #pragma unroll
            for (int j = 0; j < 8; ++j)
                t0[j] = *reinterpret_cast<const uint4*>(vg + j * 8);
            #pragma unroll
            for (int j = 0; j < 8; ++j) {
                const u16* pp = (const u16*)&t0[j];
                #pragma unroll
                for (int m = 0; m < 8; ++m) {
                    const int e = veb + j * 8 + m;
                    VsT[e * 64 + swz(e, vr)] = pp[m];
                }
            }
        }
        __syncthreads();

        // ---- Phase 3: kvsum += KsT^T VsT per head via MFMA (b128 frags). --
        #pragma unroll
        for (int hh = 0; hh < 2; ++hh) {
            const int cb = (wv * 2 + hh) * 32;
            const int da = cb + l15, dbx = cb + 16 + l15;
            #pragma unroll
            for (int kk = 0; kk < 64; kk += 32) {
                const int ko = kk + lq * 8;
                const short8 a0 = *reinterpret_cast<const short8*>(
                    &KsT[da * 64 + swz(da, ko)]);
                const short8 a1 = *reinterpret_cast<const short8*>(
                    &KsT[dbx * 64 + swz(dbx, ko)]);
                const short8 b0 = *reinterpret_cast<const short8*>(
                    &VsT[da * 64 + swz(da, ko)]);
                const short8 b1 = *reinterpret_cast<const short8*>(
                    &VsT[dbx * 64 + swz(dbx, ko)]);
                cc[hh][0] = __builtin_amdgcn_mfma_f32_16x16x32_bf16(a0, b0, cc[hh][0], 0, 0, 0);
                cc[hh][1] = __builtin_amdgcn_mfma_f32_16x16x32_bf16(a0, b1, cc[hh][1], 0, 0, 0);
                cc[hh][2] = __builtin_amdgcn_mfma_f32_16x16x32_bf16(a1, b0, cc[hh][2], 0, 0, 0);
                cc[hh][3] = __builtin_amdgcn_mfma_f32_16x16x32_bf16(a1, b1, cc[hh][3], 0, 0, 0);
            }
        }
        __syncthreads();
    }

    // ---- Atomics once per block (2-slot hash halves contention). ----------
    const int slot = blockIdx.x & 1;
    float* ksb = ksm + (size_t)(slot * 16 + b) * 256;
    #pragma unroll
    for (int j = 0; j < 4; ++j)
        if (lane < 16)
            atomicAdd(&ksb[wn + j * 16 + lane], ksp[j]);
    #pragma unroll
    for (int hh = 0; hh < 2; ++hh) {
        const int h = wv * 2 + hh;
        float* base = kvsm + ((size_t)(slot * 16 + b) * 8 + h) * 1024;
        #pragma unroll
        for (int rg = 0; rg < 4; ++rg) {
            const int d0 = lq * 4 + rg;
            atomicAdd(&base[(size_t)d0 * 32 + l15],             cc[hh][0][rg]);
            atomicAdd(&base[(size_t)d0 * 32 + 16 + l15],        cc[hh][1][rg]);
            atomicAdd(&base[(size_t)(d0 + 16) * 32 + l15],      cc[hh][2][rg]);
            atomicAdd(&base[(size_t)(d0 + 16) * 32 + 16 + l15], cc[hh][3][rg]);
        }
    }
}

// ---------------------------------------------------------------------------
// attn IN-PLACE on qy (sums the 2 kvsum/ksum slots).
// ---------------------------------------------------------------------------
__global__ __launch_bounds__(256)
void attn_kernel(u16* qy, const float* __restrict__ kvsum,
                 const float* __restrict__ ksum)
{
    __shared__ float kvs[8][32][32];
    __shared__ float km[8][32];
    __shared__ float qs[16][256];
    const int tid = threadIdx.x;
    const int b   = blockIdx.x >> 8;
    const int n0  = (blockIdx.x & 255) * 16;
    const float inv_n = 1.0f / 4096.0f;
    for (int i = tid; i < 8 * 32 * 32; i += 256)
        (&kvs[0][0][0])[i] = (kvsum[(size_t)b * 8192 + i] +
                              kvsum[(size_t)(16 + b) * 8192 + i]) * inv_n;
    (&km[0][0])[tid] = (ksum[(size_t)b * 256 + tid] +
                        ksum[(size_t)(16 + b) * 256 + tid]) * inv_n;
    u16* qb = qy + ((size_t)b * 4096 + n0) * 256;
    #pragma unroll
    for (int t = 0; t < 16; ++t)
        qs[t][tid] = b2f(qb[(size_t)t * 256 + tid]);
    __syncthreads();
    const int h = tid >> 5, e = tid & 31;
    for (int t = 0; t < 16; ++t) {
        float acc = 0.f, zd = 0.f;
        #pragma unroll
        for (int d = 0; d < 32; ++d) {
            const float qv = qs[t][h * 32 + d];
            acc = fmaf(qv, kvs[h][d][e], acc);
            zd  = fmaf(qv, km[h][d], zd);
        }
        qb[(size_t)t * 256 + tid] = f2b(acc / (zd + 1e-6f));
    }
}

// ---------------------------------------------------------------------------
// Depthwise 5x5 conv: LDS-staged 12x12x256 halo tile, thread=channel,
// register sliding 5x12 window, 8x8 outputs/thread, += into y with bias.
// ---------------------------------------------------------------------------
__global__ __launch_bounds__(256, 2)
void conv_add_kernel(const u16* __restrict__ v, const void* __restrict__ w,
                     const void* __restrict__ bias, u16* __restrict__ y,
                     const int* __restrict__ flagp)
{
    const int f32 = *flagp;
    __shared__ u16 vt[144 * 256];   // [py*12+px][ch], 73728 B
    __shared__ float wl[800];
    __shared__ float bl[32];
    const int tid = threadIdx.x;
    for (int i = tid; i < 800; i += 256) wl[i] = ldv(w, i, f32);
    if (tid < 32) bl[tid] = ldv(bias, tid, f32);

    const int bb = blockIdx.x >> 6;
    const int ty = (blockIdx.x >> 3) & 7;
    const int tx = blockIdx.x & 7;
    const int y0 = ty * 8, x0 = tx * 8;
    const u16* vb = v + (size_t)bb * 4096 * 256;

    #pragma unroll
    for (int it = 0; it < 18; ++it) {
        const int idx = it * 256 + tid;       // 0..4607
        const int px  = idx >> 5;             // 0..143
        const int c8  = (idx & 31) * 8;
        const int py  = px / 12, pxx = px - py * 12;
        const int yy = y0 + py - 2, xx = x0 + pxx - 2;
        uint4 val = {0u, 0u, 0u, 0u};
        if (yy >= 0 && yy < 64 && xx >= 0 && xx < 64)
            val = *reinterpret_cast<const uint4*>(
                vb + (size_t)((yy << 6) + xx) * 256 + c8);
        *reinterpret_cast<uint4*>(&vt[px * 256 + c8]) = val;
    }
    __syncthreads();

    const int c  = tid;            // channel
    const int dc = c & 31;
    float wreg[25];
    #pragma unroll
    for (int i = 0; i < 25; ++i) wreg[i] = wl[dc * 25 + i];
    const float bv = bl[dc];

    float win[5][12];
    #pragma unroll
    for (int r = 0; r < 5; ++r)
        #pragma unroll
        for (int cc = 0; cc < 12; ++cc)
            win[r][cc] = b2f(vt[(r * 12 + cc) * 256 + c]);

    u16* yb = y + ((size_t)bb * 4096 + (size_t)y0 * 64 + x0) * 256 + c;
    #pragma unroll
    for (int oy = 0; oy < 8; ++oy) {
        if (oy) {
            #pragma unroll
            for (int r = 0; r < 4; ++r)
                #pragma unroll
                for (int cc = 0; cc < 12; ++cc) win[r][cc] = win[r + 1][cc];
            #pragma unroll
            for (int cc = 0; cc < 12; ++cc)
                win[4][cc] = b2f(vt[((oy + 4) * 12 + cc) * 256 + c]);
        }
        #pragma unroll
        for (int ox = 0; ox < 8; ++ox) {
            float s = 0.f;
            #pragma unroll
            for (int ky = 0; ky < 5; ++ky)
                #pragma unroll
                for (int kx = 0; kx < 5; ++kx)
                    s = fmaf(win[ky][ox + kx], wreg[ky * 5 + kx], s);
            u16* yp = yb + (size_t)(oy * 64 + ox) * 256;
            *yp = f2b(b2f(*yp) + s + bv);
        }
    }
}

// ---------------------------------------------------------------------------
extern "C" void kernel_launch(void* const* d_in, const int* in_sizes, int n_in,
                              void* d_out, int out_size, void* d_ws, size_t ws_size,
                              hipStream_t stream)
{
    (void)in_sizes; (void)n_in; (void)out_size; (void)ws_size;
    const void* x   = d_in[0];
    const void* Wq  = d_in[1];
    const void* Wkv = d_in[2];
    const void* Wp  = d_in[3];
    const void* bp  = d_in[4];
    const void* sp  = d_in[5];
    const void* pe  = d_in[6];
    const void* dw  = d_in[7];
    const void* db  = d_in[8];

    // ws layout (~38 MB):
    // [flag 64B][kvsm 1M (2 slots)][ksm 32K (2 slots)][WqT 128K][WkvT 256K]
    // [WpT 128K][peb 2M][qy 33.5M]
    int*   flag = (int*)d_ws;
    float* kvsm = (float*)((char*)d_ws + 64);
    float* ksm  = kvsm + 262144;
    u16*   WqT  = (u16*)(ksm + 8192);
    u16*   WkvT = WqT + 65536;
    u16*   WpT  = WkvT + 131072;
    u16*   peb  = WpT + 65536;
    u16*   qy   = peb + 1048576;
    // v (bf16, 33.5 MB) parked at the START of d_out (dead before the final
    // GEMM overwrites d_out).
    u16*   v    = (u16*)d_out;

    hipMemsetAsync(kvsm, 0, (262144 + 8192) * sizeof(float), stream);
    detect_kernel<<<1, 64, 0, stream>>>(x, flag);
    pecvt_kernel<<<1024, 256, 0, stream>>>(pe, peb, flag);
    wtrans_kernel<<<64, 256, 0, stream>>>(Wq, WqT, 256, flag);
    wtrans_kernel<<<128, 256, 0, stream>>>(Wkv, WkvT, 512, flag);
    wtrans_kernel<<<64, 256, 0, stream>>>(Wp, WpT, 256, flag);

    // q = focus(x @ Wq)
    hipLaunchKernelGGL((gemm256<3>), dim3(512), dim3(256), 0, stream,
                       x, (const u16*)nullptr, WqT, qy, sp, flag);
    // v = x @ Wkv[:, 256:]
    hipLaunchKernelGGL((gemm256<0>), dim3(512), dim3(256), 0, stream,
                       x, (const u16*)nullptr, WkvT + (size_t)256 * 256, v,
                       (const void*)nullptr, flag);
    // fused k path: gemm + pe + focus + kvsum/ksum (k never materialized)
    fusedk_kernel<<<512, 256, 0, stream>>>(x, WkvT, peb, v, sp, kvsm, ksm, flag);

    attn_kernel<<<4096, 256, 0, stream>>>(qy, kvsm, ksm);
    conv_add_kernel<<<1024, 256, 0, stream>>>(v, dw, db, qy, flag);
    hipLaunchKernelGGL((gemm256<2>), dim3(512), dim3(256), 0, stream,
                       (const void*)nullptr, qy, WpT, (u16*)d_out, bp, flag);
}

// Round 5
// 358.579 us; speedup vs baseline: 1.2677x; 1.0326x over previous
//
#include <hip/hip_runtime.h>
#include <hip/hip_bf16.h>

typedef unsigned short u16;
using bf16_t = __hip_bfloat16;
typedef short short8 __attribute__((ext_vector_type(8)));
typedef float f32x4 __attribute__((ext_vector_type(4)));

__device__ __forceinline__ float b2f(u16 u) {
    return __uint_as_float((unsigned int)u << 16);
}
__device__ __forceinline__ u16 f2b(float f) {
    bf16_t h = __float2bfloat16(f);
    union { bf16_t h; u16 u; } cv; cv.h = h; return cv.u;
}
__device__ __forceinline__ float ldv(const void* p, size_t i, int f32) {
    return f32 ? ((const float*)p)[i] : b2f(((const u16*)p)[i]);
}
__device__ __forceinline__ uint4 pack8(float4 a, float4 b) {
    uint4 u;
    u.x = (unsigned)f2b(a.x) | ((unsigned)f2b(a.y) << 16);
    u.y = (unsigned)f2b(a.z) | ((unsigned)f2b(a.w) << 16);
    u.z = (unsigned)f2b(b.x) | ((unsigned)f2b(b.y) << 16);
    u.w = (unsigned)f2b(b.z) | ((unsigned)f2b(b.w) << 16);
    return u;
}
// XOR swizzle for stride-64(u16) LDS tiles: element (n,k) lives at
// n*64 + (k ^ ((n&7)<<3)). Bijective within each row; 16B blocks preserved.
__device__ __forceinline__ int swz(int n, int k) {
    return k ^ ((n & 7) << 3);
}
// Async global->LDS DMA, 16B per lane. LDS dest must be wave-uniform base;
// HW writes lane i at base + i*16B. Global src is per-lane (pre-swizzled).
__device__ __forceinline__ void gl16(const u16* g, u16* l) {
    __builtin_amdgcn_global_load_lds(
        (const __attribute__((address_space(1))) unsigned int*)g,
        (__attribute__((address_space(3))) unsigned int*)l, 16, 0, 0);
}

// ---------------------------------------------------------------------------
// Input-dtype detector (flag=1 -> fp32 inputs & fp32 output).
// ---------------------------------------------------------------------------
__global__ void detect_kernel(const void* __restrict__ x, int* __restrict__ flag)
{
    const int t = threadIdx.x;
    const u16 h = ((const u16*)x)[2 * t];
    const int e = (h >> 7) & 0xFF;
    const int plaus = (e >= 112 && e <= 133) ? 1 : 0;
    const unsigned long long m = __ballot(plaus);
    if (t == 0) flag[0] = (__popcll(m) < 32) ? 1 : 0;
}

// x -> xb (bf16 always). 8 elements/thread.
__global__ __launch_bounds__(256)
void xcvt_kernel(const void* __restrict__ x, u16* __restrict__ xb,
                 const int* __restrict__ flagp)
{
    const size_t i = ((size_t)blockIdx.x * 256 + threadIdx.x) * 8;
    if (*flagp) {
        const float* xf = (const float*)x + i;
        const float4 f0 = *reinterpret_cast<const float4*>(xf);
        const float4 f1 = *reinterpret_cast<const float4*>(xf + 4);
        *reinterpret_cast<uint4*>(xb + i) = pack8(f0, f1);
    } else {
        *reinterpret_cast<uint4*>(xb + i) =
            *reinterpret_cast<const uint4*>((const u16*)x + i);
    }
}

// pe -> peb (bf16 always).
__global__ __launch_bounds__(256)
void pecvt_kernel(const void* __restrict__ pe, u16* __restrict__ peb,
                  const int* __restrict__ flagp)
{
    const size_t i = ((size_t)blockIdx.x * 256 + threadIdx.x) * 4;
    if (*flagp) {
        const float4 f = *reinterpret_cast<const float4*>((const float*)pe + i);
        ushort4 o; o.x = f2b(f.x); o.y = f2b(f.y); o.z = f2b(f.z); o.w = f2b(f.w);
        *reinterpret_cast<ushort4*>(peb + i) = o;
    } else {
        *reinterpret_cast<ushort4*>(peb + i) =
            *reinterpret_cast<const ushort4*>((const u16*)pe + i);
    }
}

// W[K x N] -> WT[N x K(=256)] bf16, LDS-tiled transpose.
__global__ __launch_bounds__(256)
void wtrans_kernel(const void* __restrict__ W, u16* __restrict__ WT, int N,
                   const int* __restrict__ flagp)
{
    const int f32 = *flagp;
    __shared__ float tile[32][33];
    const int tx = threadIdx.x & 31, ty = threadIdx.x >> 5;   // ty 0..7
    const int bx = blockIdx.x % (N >> 5);   // n tile
    const int by = blockIdx.x / (N >> 5);   // k tile
    #pragma unroll
    for (int r = 0; r < 4; ++r) {
        const int k = by * 32 + ty + r * 8;
        const int n = bx * 32 + tx;
        tile[ty + r * 8][tx] = ldv(W, (size_t)k * N + n, f32);
    }
    __syncthreads();
    #pragma unroll
    for (int r = 0; r < 4; ++r) {
        const int n2 = bx * 32 + ty + r * 8;
        const int k2 = by * 32 + tx;
        WT[(size_t)n2 * 256 + k2] = f2b(tile[tx][ty + r * 8]);
    }
}

// ---------------------------------------------------------------------------
// MFMA GEMM, BN=256: O[rows x 256] = A[rows x 256] @ B. 128x256 block tile,
// BK=64, 4 waves 2(m)x2(n), wave tile 64x128 (acc[4][8]).
// B always staged via global_load_lds into linear stride-64 LDS with
// XOR-pre-swizzled global source. A likewise when bf16 (MODE 2, abf=1, or
// flag=0); fp32 A converts in VGPRs and writes swizzled.
// MODE 0: O0(bf16) = A@B                      (v-gemm)
// MODE 2: out = A@B + bias; fp32/bf16 store   (A = qy bf16)
// MODE 3: O0(bf16) = focus(A@B)               (q-gemm, focus fused)
// ---------------------------------------------------------------------------
template<int MODE>
__global__ __launch_bounds__(256, 2)
void gemm256(const void* __restrict__ Aany, const u16* __restrict__ Abf,
             const u16* __restrict__ BT, u16* __restrict__ O0,
             const void* __restrict__ extra, const int* __restrict__ flagp,
             int abf)
{
    const int f32 = *flagp;
    __shared__ u16 As[128 * 64];     // linear, swizzled content
    __shared__ u16 Bs[256 * 64];
    __shared__ float red2[2][128];
    __shared__ float red6[2][128];
    __shared__ float ratio_s[128];
    __shared__ float sscr[256];

    const int tid  = threadIdx.x;
    const int row0 = blockIdx.x * 128;
    const int lane = tid & 63;
    const int wv   = tid >> 6;
    const int wvu  = __builtin_amdgcn_readfirstlane(wv);
    const int wm   = (wv & 1) * 64;          // wave row base
    const int wn   = (wv >> 1) * 128;        // wave col base
    const int l15  = lane & 15;
    const int lq   = lane >> 4;
    const int lr8  = lane >> 3;              // staging: row within 8-group
    const int lc8  = (lane & 7) * 8;         // staging: col (u16) within row

    if (MODE == 3) {
        const float p = ldv(extra, tid, f32);
        const float s = (p > 20.f) ? p : log1pf(expf(p));
        sscr[tid] = 1.0f / s;
    }

    f32x4 acc[4][8] = {};

    for (int k0 = 0; k0 < 256; k0 += 64) {
        // ---- B stage: wave w rows [w*64, w*64+64), 8 DMA instrs. ----------
        #pragma unroll
        for (int it = 0; it < 8; ++it) {
            const int r = wvu * 64 + it * 8 + lr8;
            gl16(BT + (size_t)r * 256 + k0 + swz(r, lc8),
                 &Bs[(wvu * 64 + it * 8) * 64]);
        }
        // ---- A stage ------------------------------------------------------
        if (MODE == 2 || abf || !f32) {
            const u16* Ab = (MODE == 2) ? Abf : (const u16*)Aany;
            #pragma unroll
            for (int it = 0; it < 4; ++it) {
                const int r = wvu * 32 + it * 8 + lr8;
                gl16(Ab + (size_t)(row0 + r) * 256 + k0 + swz(r, lc8),
                     &As[(wvu * 32 + it * 8) * 64]);
            }
        } else {
            const int sr = tid >> 1;              // row 0..127
            const int sk = (tid & 1) * 32;        // k-half
            const float* ag = (const float*)Aany +
                              (size_t)(row0 + sr) * 256 + k0 + sk;
            #pragma unroll
            for (int j = 0; j < 4; ++j) {
                const float4 f0 = *reinterpret_cast<const float4*>(ag + j * 8);
                const float4 f1 = *reinterpret_cast<const float4*>(ag + j * 8 + 4);
                *reinterpret_cast<uint4*>(
                    &As[sr * 64 + swz(sr, sk + j * 8)]) = pack8(f0, f1);
            }
        }
        __syncthreads();
        #pragma unroll
        for (int ks = 0; ks < 64; ks += 32) {
            const int ko = ks + lq * 8;
            short8 av[4], bv[8];
            #pragma unroll
            for (int i = 0; i < 4; ++i) {
                const int m = wm + i * 16 + l15;
                av[i] = *reinterpret_cast<const short8*>(&As[m * 64 + swz(m, ko)]);
            }
            #pragma unroll
            for (int j = 0; j < 8; ++j) {
                const int n = wn + j * 16 + l15;
                bv[j] = *reinterpret_cast<const short8*>(&Bs[n * 64 + swz(n, ko)]);
            }
            #pragma unroll
            for (int i = 0; i < 4; ++i)
                #pragma unroll
                for (int j = 0; j < 8; ++j)
                    acc[i][j] = __builtin_amdgcn_mfma_f32_16x16x32_bf16(
                        av[i], bv[j], acc[i][j], 0, 0, 0);
        }
        __syncthreads();
    }

    if (MODE == 3) {
        // focus: xv=(relu+eps)/softplus; per-row s2=sum xv^2, s6=sum xv^6.
        #pragma unroll
        for (int i = 0; i < 4; ++i) {
            #pragma unroll
            for (int rg = 0; rg < 4; ++rg) {
                const int lr = wm + i * 16 + lq * 4 + rg;   // local row 0..127
                float s2 = 0.f, s6 = 0.f;
                #pragma unroll
                for (int j = 0; j < 8; ++j) {
                    const int col = wn + j * 16 + l15;
                    const float xv =
                        (fmaxf(acc[i][j][rg], 0.f) + 1e-6f) * sscr[col];
                    acc[i][j][rg] = xv;
                    const float x2 = xv * xv;
                    s2 += x2;
                    s6 += x2 * x2 * x2;
                }
                #pragma unroll
                for (int off = 1; off < 16; off <<= 1) {
                    s2 += __shfl_xor(s2, off);
                    s6 += __shfl_xor(s6, off);
                }
                if (l15 == 0) { red2[wv >> 1][lr] = s2; red6[wv >> 1][lr] = s6; }
            }
        }
        __syncthreads();
        if (tid < 128)
            ratio_s[tid] = sqrtf((red2[0][tid] + red2[1][tid]) /
                                 (red6[0][tid] + red6[1][tid]));
        __syncthreads();
    }

    // Store. C/D layout: row=(lane>>4)*4+reg, col=lane&15 (m89-verified).
    #pragma unroll
    for (int i = 0; i < 4; ++i) {
        #pragma unroll
        for (int j = 0; j < 8; ++j) {
            const int gcol = wn + j * 16 + l15;
            #pragma unroll
            for (int rg = 0; rg < 4; ++rg) {
                const int lr = wm + i * 16 + lq * 4 + rg;
                const size_t oi = (size_t)(row0 + lr) * 256 + gcol;
                const float a = acc[i][j][rg];
                if (MODE == 0) {
                    O0[oi] = f2b(a);
                } else if (MODE == 3) {
                    O0[oi] = f2b(a * a * a * ratio_s[lr]);
                } else {
                    const float o = a + ldv(extra, gcol, f32);
                    if (f32) ((float*)O0)[oi] = o;
                    else     O0[oi] = f2b(o);
                }
            }
        }
    }
}

// ---------------------------------------------------------------------------
// Fused k-path v3 (chunk-merged): k = x @ Wkv[:, :256] + pe -> focus ->
// kvsum/ksum atomics. Both 64-row chunks computed in ONE K-loop sharing each
// B stage (B traffic and barriers halve; 64 MFMA/wave between barriers).
// acc[2][4][4] (128 VGPR). Phase 2/3 per chunk as verified in rounds 2-4.
// LDS union: GEMM {As[128][64] 16K | Bs[256][64] 32K} / phase23 {KsT 32K |
// VsT 32K} = 64 KB -> 2 blocks/CU.
// ---------------------------------------------------------------------------
__global__ __launch_bounds__(256, 2)
void fusedk_kernel(const void* __restrict__ x, const u16* __restrict__ WkvT,
                   const u16* __restrict__ peb, const u16* __restrict__ v,
                   const void* __restrict__ sp,
                   float* __restrict__ kvsm, float* __restrict__ ksm,
                   const int* __restrict__ flagp, int abf)
{
    const int f32 = *flagp;
    __shared__ u16 smem[32768];          // 64 KB, phase-aliased
    __shared__ float red2[4][64];
    __shared__ float red6[4][64];
    __shared__ float ratio_s[64];
    __shared__ float sscr[256];
    u16* As  = smem;                     // [128][64]  (GEMM)
    u16* Bs  = smem + 8192;              // [256][64]  (GEMM)
    u16* KsT = smem;                     // [256][64]  (phase 2b/3)
    u16* VsT = smem + 16384;             // [256][64]  (phase 3)

    const int tid  = threadIdx.x;
    const int lane = tid & 63;
    const int wv   = tid >> 6;           // 0..3
    const int wvu  = __builtin_amdgcn_readfirstlane(wv);
    const int l15  = lane & 15;
    const int lq   = lane >> 4;
    const int wn   = wv * 64;
    const int lr8  = lane >> 3;
    const int lc8  = (lane & 7) * 8;

    {
        const float p = ldv(sp, tid, f32);
        const float s = (p > 20.f) ? p : log1pf(expf(p));
        sscr[tid] = 1.0f / s;
    }

    f32x4 cc[2][4] = {};                 // kvsum accum (2 heads/wave)
    float ksp[4] = {0.f, 0.f, 0.f, 0.f}; // ksum accum

    const int b    = blockIdx.x >> 5;    // batch (128 rows/block)
    const int row0 = blockIdx.x * 128;
    const int vr   = lane;               // V staging row
    const int veb  = wv * 64;            // V staging col base

    // ---- Phase 1: GEMM, both chunks, shared B staging. --------------------
    f32x4 acc[2][4][4] = {};
    for (int k0 = 0; k0 < 256; k0 += 64) {
        #pragma unroll
        for (int it = 0; it < 8; ++it) {
            const int r = wvu * 64 + it * 8 + lr8;
            gl16(WkvT + (size_t)r * 256 + k0 + swz(r, lc8),
                 &Bs[(wvu * 64 + it * 8) * 64]);
        }
        if (abf || !f32) {
            #pragma unroll
            for (int it = 0; it < 4; ++it) {
                const int r = wvu * 32 + it * 8 + lr8;
                gl16((const u16*)x + (size_t)(row0 + r) * 256 + k0 + swz(r, lc8),
                     &As[(wvu * 32 + it * 8) * 64]);
            }
        } else {
            const int sr = tid >> 1;              // row 0..127
            const int sk = (tid & 1) * 32;        // k-half
            const float* ag = (const float*)x +
                              (size_t)(row0 + sr) * 256 + k0 + sk;
            #pragma unroll
            for (int j = 0; j < 4; ++j) {
                const float4 f0 = *reinterpret_cast<const float4*>(ag + j * 8);
                const float4 f1 = *reinterpret_cast<const float4*>(ag + j * 8 + 4);
                *reinterpret_cast<uint4*>(
                    &As[sr * 64 + swz(sr, sk + j * 8)]) = pack8(f0, f1);
            }
        }
        __syncthreads();
        #pragma unroll
        for (int c = 0; c < 2; ++c) {
            #pragma unroll
            for (int ks = 0; ks < 64; ks += 32) {
                const int ko = ks + lq * 8;
                short8 av[4], bvv[4];
                #pragma unroll
                for (int i = 0; i < 4; ++i) {
                    const int m = c * 64 + i * 16 + l15;
                    av[i] = *reinterpret_cast<const short8*>(&As[m * 64 + swz(m, ko)]);
                }
                #pragma unroll
                for (int j = 0; j < 4; ++j) {
                    const int n = wn + j * 16 + l15;
                    bvv[j] = *reinterpret_cast<const short8*>(&Bs[n * 64 + swz(n, ko)]);
                }
                #pragma unroll
                for (int i = 0; i < 4; ++i)
                    #pragma unroll
                    for (int j = 0; j < 4; ++j)
                        acc[c][i][j] = __builtin_amdgcn_mfma_f32_16x16x32_bf16(
                            av[i], bvv[j], acc[c][i][j], 0, 0, 0);
            }
        }
        __syncthreads();
    }

    // ---- Phases 2-3 per chunk. --------------------------------------------
    #pragma unroll
    for (int c = 0; c < 2; ++c) {
        const int nb = (row0 & 4095) + c * 64;

        // Phase 2a: +peb, normalize, s2/s6 reduce.
        #pragma unroll
        for (int i = 0; i < 4; ++i) {
            #pragma unroll
            for (int rg = 0; rg < 4; ++rg) {
                const int lrow = i * 16 + lq * 4 + rg;
                float s2 = 0.f, s6 = 0.f;
                #pragma unroll
                for (int j = 0; j < 4; ++j) {
                    const int col = wn + j * 16 + l15;
                    const float t = acc[c][i][j][rg] +
                        b2f(peb[(size_t)(nb + lrow) * 256 + col]);
                    const float xv = (fmaxf(t, 0.f) + 1e-6f) * sscr[col];
                    acc[c][i][j][rg] = xv;
                    const float x2 = xv * xv;
                    s2 += x2;
                    s6 += x2 * x2 * x2;
                }
                #pragma unroll
                for (int off = 1; off < 16; off <<= 1) {
                    s2 += __shfl_xor(s2, off);
                    s6 += __shfl_xor(s6, off);
                }
                if (l15 == 0) { red2[wv][lrow] = s2; red6[wv][lrow] = s6; }
            }
        }
        __syncthreads();
        if (tid < 64) {
            const float s2t = red2[0][tid] + red2[1][tid] + red2[2][tid] + red2[3][tid];
            const float s6t = red6[0][tid] + red6[1][tid] + red6[2][tid] + red6[3][tid];
            ratio_s[tid] = sqrtf(s2t / s6t);
        }
        __syncthreads();

        // Phase 2b: finalize k -> KsT[d][r] (swz); ksum partials.
        {
            float kscol[4] = {0.f, 0.f, 0.f, 0.f};
            #pragma unroll
            for (int i = 0; i < 4; ++i)
                #pragma unroll
                for (int rg = 0; rg < 4; ++rg) {
                    const int lrow = i * 16 + lq * 4 + rg;
                    const float rt = ratio_s[lrow];
                    #pragma unroll
                    for (int j = 0; j < 4; ++j) {
                        const float xv = acc[c][i][j][rg];
                        const float kf = xv * xv * xv * rt;
                        const int d = wn + j * 16 + l15;
                        KsT[d * 64 + swz(d, lrow)] = f2b(kf);
                        kscol[j] += kf;
                    }
                }
            #pragma unroll
            for (int j = 0; j < 4; ++j) {
                float kp = kscol[j];
                kp += __shfl_xor(kp, 16);
                kp += __shfl_xor(kp, 32);
                ksp[j] += kp;
            }
        }

        // Stage V transposed: VsT[e][r] (swz).
        {
            const u16* vg = v + (size_t)(row0 + c * 64 + vr) * 256 + veb;
            uint4 t0[8];
            #pragma unroll
            for (int j = 0; j < 8; ++j)
                t0[j] = *reinterpret_cast<const uint4*>(vg + j * 8);
            #pragma unroll
            for (int j = 0; j < 8; ++j) {
                const u16* pp = (const u16*)&t0[j];
                #pragma unroll
                for (int m = 0; m < 8; ++m) {
                    const int e = veb + j * 8 + m;
                    VsT[e * 64 + swz(e, vr)] = pp[m];
                }
            }
        }
        __syncthreads();

        // Phase 3: kvsum += KsT^T VsT per head via MFMA (b128 frags).
        #pragma unroll
        for (int hh = 0; hh < 2; ++hh) {
            const int cb = (wv * 2 + hh) * 32;
            const int da = cb + l15, dbx = cb + 16 + l15;
            #pragma unroll
            for (int kk = 0; kk < 64; kk += 32) {
                const int ko = kk + lq * 8;
                const short8 a0 = *reinterpret_cast<const short8*>(
                    &KsT[da * 64 + swz(da, ko)]);
                const short8 a1 = *reinterpret_cast<const short8*>(
                    &KsT[dbx * 64 + swz(dbx, ko)]);
                const short8 b0 = *reinterpret_cast<const short8*>(
                    &VsT[da * 64 + swz(da, ko)]);
                const short8 b1 = *reinterpret_cast<const short8*>(
                    &VsT[dbx * 64 + swz(dbx, ko)]);
                cc[hh][0] = __builtin_amdgcn_mfma_f32_16x16x32_bf16(a0, b0, cc[hh][0], 0, 0, 0);
                cc[hh][1] = __builtin_amdgcn_mfma_f32_16x16x32_bf16(a0, b1, cc[hh][1], 0, 0, 0);
                cc[hh][2] = __builtin_amdgcn_mfma_f32_16x16x32_bf16(a1, b0, cc[hh][2], 0, 0, 0);
                cc[hh][3] = __builtin_amdgcn_mfma_f32_16x16x32_bf16(a1, b1, cc[hh][3], 0, 0, 0);
            }
        }
        __syncthreads();
    }

    // ---- Atomics once per block (2-slot hash halves contention). ----------
    const int slot = blockIdx.x & 1;
    float* ksb = ksm + (size_t)(slot * 16 + b) * 256;
    #pragma unroll
    for (int j = 0; j < 4; ++j)
        if (lane < 16)
            atomicAdd(&ksb[wn + j * 16 + lane], ksp[j]);
    #pragma unroll
    for (int hh = 0; hh < 2; ++hh) {
        const int h = wv * 2 + hh;
        float* base = kvsm + ((size_t)(slot * 16 + b) * 8 + h) * 1024;
        #pragma unroll
        for (int rg = 0; rg < 4; ++rg) {
            const int d0 = lq * 4 + rg;
            atomicAdd(&base[(size_t)d0 * 32 + l15],             cc[hh][0][rg]);
            atomicAdd(&base[(size_t)d0 * 32 + 16 + l15],        cc[hh][1][rg]);
            atomicAdd(&base[(size_t)(d0 + 16) * 32 + l15],      cc[hh][2][rg]);
            atomicAdd(&base[(size_t)(d0 + 16) * 32 + 16 + l15], cc[hh][3][rg]);
        }
    }
}

// ---------------------------------------------------------------------------
// attn IN-PLACE on qy (sums the 2 kvsum/ksum slots).
// ---------------------------------------------------------------------------
__global__ __launch_bounds__(256)
void attn_kernel(u16* qy, const float* __restrict__ kvsum,
                 const float* __restrict__ ksum)
{
    __shared__ float kvs[8][32][32];
    __shared__ float km[8][32];
    __shared__ float qs[16][256];
    const int tid = threadIdx.x;
    const int b   = blockIdx.x >> 8;
    const int n0  = (blockIdx.x & 255) * 16;
    const float inv_n = 1.0f / 4096.0f;
    for (int i = tid; i < 8 * 32 * 32; i += 256)
        (&kvs[0][0][0])[i] = (kvsum[(size_t)b * 8192 + i] +
                              kvsum[(size_t)(16 + b) * 8192 + i]) * inv_n;
    (&km[0][0])[tid] = (ksum[(size_t)b * 256 + tid] +
                        ksum[(size_t)(16 + b) * 256 + tid]) * inv_n;
    u16* qb = qy + ((size_t)b * 4096 + n0) * 256;
    #pragma unroll
    for (int t = 0; t < 16; ++t)
        qs[t][tid] = b2f(qb[(size_t)t * 256 + tid]);
    __syncthreads();
    const int h = tid >> 5, e = tid & 31;
    for (int t = 0; t < 16; ++t) {
        float acc = 0.f, zd = 0.f;
        #pragma unroll
        for (int d = 0; d < 32; ++d) {
            const float qv = qs[t][h * 32 + d];
            acc = fmaf(qv, kvs[h][d][e], acc);
            zd  = fmaf(qv, km[h][d], zd);
        }
        qb[(size_t)t * 256 + tid] = f2b(acc / (zd + 1e-6f));
    }
}

// ---------------------------------------------------------------------------
// Depthwise 5x5 conv: LDS-staged 12x12x256 halo tile, thread=channel,
// register sliding 5x12 window, 8x8 outputs/thread, += into y with bias.
// ---------------------------------------------------------------------------
__global__ __launch_bounds__(256, 2)
void conv_add_kernel(const u16* __restrict__ v, const void* __restrict__ w,
                     const void* __restrict__ bias, u16* __restrict__ y,
                     const int* __restrict__ flagp)
{
    const int f32 = *flagp;
    __shared__ u16 vt[144 * 256];   // [py*12+px][ch], 73728 B
    __shared__ float wl[800];
    __shared__ float bl[32];
    const int tid = threadIdx.x;
    for (int i = tid; i < 800; i += 256) wl[i] = ldv(w, i, f32);
    if (tid < 32) bl[tid] = ldv(bias, tid, f32);

    const int bb = blockIdx.x >> 6;
    const int ty = (blockIdx.x >> 3) & 7;
    const int tx = blockIdx.x & 7;
    const int y0 = ty * 8, x0 = tx * 8;
    const u16* vb = v + (size_t)bb * 4096 * 256;

    #pragma unroll
    for (int it = 0; it < 18; ++it) {
        const int idx = it * 256 + tid;       // 0..4607
        const int px  = idx >> 5;             // 0..143
        const int c8  = (idx & 31) * 8;
        const int py  = px / 12, pxx = px - py * 12;
        const int yy = y0 + py - 2, xx = x0 + pxx - 2;
        uint4 val = {0u, 0u, 0u, 0u};
        if (yy >= 0 && yy < 64 && xx >= 0 && xx < 64)
            val = *reinterpret_cast<const uint4*>(
                vb + (size_t)((yy << 6) + xx) * 256 + c8);
        *reinterpret_cast<uint4*>(&vt[px * 256 + c8]) = val;
    }
    __syncthreads();

    const int c  = tid;            // channel
    const int dc = c & 31;
    float wreg[25];
    #pragma unroll
    for (int i = 0; i < 25; ++i) wreg[i] = wl[dc * 25 + i];
    const float bv = bl[dc];

    float win[5][12];
    #pragma unroll
    for (int r = 0; r < 5; ++r)
        #pragma unroll
        for (int cc = 0; cc < 12; ++cc)
            win[r][cc] = b2f(vt[(r * 12 + cc) * 256 + c]);

    u16* yb = y + ((size_t)bb * 4096 + (size_t)y0 * 64 + x0) * 256 + c;
    #pragma unroll
    for (int oy = 0; oy < 8; ++oy) {
        if (oy) {
            #pragma unroll
            for (int r = 0; r < 4; ++r)
                #pragma unroll
                for (int cc = 0; cc < 12; ++cc) win[r][cc] = win[r + 1][cc];
            #pragma unroll
            for (int cc = 0; cc < 12; ++cc)
                win[4][cc] = b2f(vt[((oy + 4) * 12 + cc) * 256 + c]);
        }
        #pragma unroll
        for (int ox = 0; ox < 8; ++ox) {
            float s = 0.f;
            #pragma unroll
            for (int ky = 0; ky < 5; ++ky)
                #pragma unroll
                for (int kx = 0; kx < 5; ++kx)
                    s = fmaf(win[ky][ox + kx], wreg[ky * 5 + kx], s);
            u16* yp = yb + (size_t)(oy * 64 + ox) * 256;
            *yp = f2b(b2f(*yp) + s + bv);
        }
    }
}

// ---------------------------------------------------------------------------
extern "C" void kernel_launch(void* const* d_in, const int* in_sizes, int n_in,
                              void* d_out, int out_size, void* d_ws, size_t ws_size,
                              hipStream_t stream)
{
    (void)in_sizes; (void)n_in; (void)out_size;
    const void* x   = d_in[0];
    const void* Wq  = d_in[1];
    const void* Wkv = d_in[2];
    const void* Wp  = d_in[3];
    const void* bp  = d_in[4];
    const void* sp  = d_in[5];
    const void* pe  = d_in[6];
    const void* dw  = d_in[7];
    const void* db  = d_in[8];

    // ws layout:
    // [flag 64B][kvsm 1M (2 slots)][ksm 32K (2 slots)][WqT 128K][WkvT 256K]
    // [WpT 128K][peb 2M][qy 32M][xb 32M (only if ws large enough)]
    int*   flag = (int*)d_ws;
    float* kvsm = (float*)((char*)d_ws + 64);
    float* ksm  = kvsm + 262144;
    u16*   WqT  = (u16*)(ksm + 8192);
    u16*   WkvT = WqT + 65536;
    u16*   WpT  = WkvT + 131072;
    u16*   peb  = WpT + 65536;
    u16*   qy   = peb + 1048576;
    u16*   xb   = qy + (size_t)16777216;
    // v (bf16, 33.5 MB) parked at the START of d_out (dead before the final
    // GEMM overwrites d_out).
    u16*   v    = (u16*)d_out;

    const size_t need = (size_t)((char*)(xb + 16777216) - (char*)d_ws);
    const int big = (ws_size >= need) ? 1 : 0;

    hipMemsetAsync(kvsm, 0, (262144 + 8192) * sizeof(float), stream);
    detect_kernel<<<1, 64, 0, stream>>>(x, flag);
    if (big) xcvt_kernel<<<8192, 256, 0, stream>>>(x, xb, flag);
    pecvt_kernel<<<1024, 256, 0, stream>>>(pe, peb, flag);
    wtrans_kernel<<<64, 256, 0, stream>>>(Wq, WqT, 256, flag);
    wtrans_kernel<<<128, 256, 0, stream>>>(Wkv, WkvT, 512, flag);
    wtrans_kernel<<<64, 256, 0, stream>>>(Wp, WpT, 256, flag);

    const void* Ax = big ? (const void*)xb : x;

    // q = focus(x @ Wq)
    hipLaunchKernelGGL((gemm256<3>), dim3(512), dim3(256), 0, stream,
                       Ax, (const u16*)nullptr, WqT, qy, sp, flag, big);
    // v = x @ Wkv[:, 256:]
    hipLaunchKernelGGL((gemm256<0>), dim3(512), dim3(256), 0, stream,
                       Ax, (const u16*)nullptr, WkvT + (size_t)256 * 256, v,
                       (const void*)nullptr, flag, big);
    // fused k path: gemm + pe + focus + kvsum/ksum (k never materialized)
    fusedk_kernel<<<512, 256, 0, stream>>>(Ax, WkvT, peb, v, sp, kvsm, ksm,
                                           flag, big);

    attn_kernel<<<4096, 256, 0, stream>>>(qy, kvsm, ksm);
    conv_add_kernel<<<1024, 256, 0, stream>>>(v, dw, db, qy, flag);
    hipLaunchKernelGGL((gemm256<2>), dim3(512), dim3(256), 0, stream,
                       (const void*)nullptr, qy, WpT, (u16*)d_out, bp, flag, 0);
}

// Round 6
// 325.516 us; speedup vs baseline: 1.3964x; 1.1016x over previous
//
#include <hip/hip_runtime.h>
#include <hip/hip_bf16.h>

typedef unsigned short u16;
using bf16_t = __hip_bfloat16;
typedef short short8 __attribute__((ext_vector_type(8)));
typedef float f32x4 __attribute__((ext_vector_type(4)));

__device__ __forceinline__ float b2f(u16 u) {
    return __uint_as_float((unsigned int)u << 16);
}
__device__ __forceinline__ u16 f2b(float f) {
    bf16_t h = __float2bfloat16(f);
    union { bf16_t h; u16 u; } cv; cv.h = h; return cv.u;
}
__device__ __forceinline__ float ldv(const void* p, size_t i, int f32) {
    return f32 ? ((const float*)p)[i] : b2f(((const u16*)p)[i]);
}
__device__ __forceinline__ uint4 pack8(float4 a, float4 b) {
    uint4 u;
    u.x = (unsigned)f2b(a.x) | ((unsigned)f2b(a.y) << 16);
    u.y = (unsigned)f2b(a.z) | ((unsigned)f2b(a.w) << 16);
    u.z = (unsigned)f2b(b.x) | ((unsigned)f2b(b.y) << 16);
    u.w = (unsigned)f2b(b.z) | ((unsigned)f2b(b.w) << 16);
    return u;
}
// XOR swizzle for stride-64(u16) LDS tiles: element (n,k) lives at
// n*64 + (k ^ ((n&7)<<3)). Bijective within each row; 16B blocks preserved.
__device__ __forceinline__ int swz(int n, int k) {
    return k ^ ((n & 7) << 3);
}
// Async global->LDS DMA, 16B per lane. LDS dest must be wave-uniform base;
// HW writes lane i at base + i*16B. Global src is per-lane (pre-swizzled).
__device__ __forceinline__ void gl16(const u16* g, u16* l) {
    __builtin_amdgcn_global_load_lds(
        (const __attribute__((address_space(1))) unsigned int*)g,
        (__attribute__((address_space(3))) unsigned int*)l, 16, 0, 0);
}

// ---------------------------------------------------------------------------
// Input-dtype detector (flag=1 -> fp32 inputs & fp32 output).
// ---------------------------------------------------------------------------
__global__ void detect_kernel(const void* __restrict__ x, int* __restrict__ flag)
{
    const int t = threadIdx.x;
    const u16 h = ((const u16*)x)[2 * t];
    const int e = (h >> 7) & 0xFF;
    const int plaus = (e >= 112 && e <= 133) ? 1 : 0;
    const unsigned long long m = __ballot(plaus);
    if (t == 0) flag[0] = (__popcll(m) < 32) ? 1 : 0;
}

// x -> xb (bf16 always). 8 elements/thread.
__global__ __launch_bounds__(256)
void xcvt_kernel(const void* __restrict__ x, u16* __restrict__ xb,
                 const int* __restrict__ flagp)
{
    const size_t i = ((size_t)blockIdx.x * 256 + threadIdx.x) * 8;
    if (*flagp) {
        const float* xf = (const float*)x + i;
        const float4 f0 = *reinterpret_cast<const float4*>(xf);
        const float4 f1 = *reinterpret_cast<const float4*>(xf + 4);
        *reinterpret_cast<uint4*>(xb + i) = pack8(f0, f1);
    } else {
        *reinterpret_cast<uint4*>(xb + i) =
            *reinterpret_cast<const uint4*>((const u16*)x + i);
    }
}

// pe -> peb (bf16 always).
__global__ __launch_bounds__(256)
void pecvt_kernel(const void* __restrict__ pe, u16* __restrict__ peb,
                  const int* __restrict__ flagp)
{
    const size_t i = ((size_t)blockIdx.x * 256 + threadIdx.x) * 4;
    if (*flagp) {
        const float4 f = *reinterpret_cast<const float4*>((const float*)pe + i);
        ushort4 o; o.x = f2b(f.x); o.y = f2b(f.y); o.z = f2b(f.z); o.w = f2b(f.w);
        *reinterpret_cast<ushort4*>(peb + i) = o;
    } else {
        *reinterpret_cast<ushort4*>(peb + i) =
            *reinterpret_cast<const ushort4*>((const u16*)pe + i);
    }
}

// W[K x N] -> WT[N x K(=256)] bf16, LDS-tiled transpose.
__global__ __launch_bounds__(256)
void wtrans_kernel(const void* __restrict__ W, u16* __restrict__ WT, int N,
                   const int* __restrict__ flagp)
{
    const int f32 = *flagp;
    __shared__ float tile[32][33];
    const int tx = threadIdx.x & 31, ty = threadIdx.x >> 5;   // ty 0..7
    const int bx = blockIdx.x % (N >> 5);   // n tile
    const int by = blockIdx.x / (N >> 5);   // k tile
    #pragma unroll
    for (int r = 0; r < 4; ++r) {
        const int k = by * 32 + ty + r * 8;
        const int n = bx * 32 + tx;
        tile[ty + r * 8][tx] = ldv(W, (size_t)k * N + n, f32);
    }
    __syncthreads();
    #pragma unroll
    for (int r = 0; r < 4; ++r) {
        const int n2 = bx * 32 + ty + r * 8;
        const int k2 = by * 32 + tx;
        WT[(size_t)n2 * 256 + k2] = f2b(tile[tx][ty + r * 8]);
    }
}

// ---------------------------------------------------------------------------
// MFMA GEMM, BN=256: O[rows x 256] = A[rows x 256] @ B. 128x256 block tile,
// BK=64, 4 waves 2(m)x2(n), wave tile 64x128 (acc[4][8]).
// MODE 0: O0(bf16) = A@B                      (v-gemm)
// MODE 2: out = A@B + bias; fp32/bf16 store   (A = qy bf16)
// MODE 3: O0(bf16) = focus(A@B)               (q-gemm, focus fused)
// ---------------------------------------------------------------------------
template<int MODE>
__global__ __launch_bounds__(256, 2)
void gemm256(const void* __restrict__ Aany, const u16* __restrict__ Abf,
             const u16* __restrict__ BT, u16* __restrict__ O0,
             const void* __restrict__ extra, const int* __restrict__ flagp,
             int abf)
{
    const int f32 = *flagp;
    __shared__ u16 As[128 * 64];     // linear, swizzled content
    __shared__ u16 Bs[256 * 64];
    __shared__ float red2[2][128];
    __shared__ float red6[2][128];
    __shared__ float ratio_s[128];
    __shared__ float sscr[256];

    const int tid  = threadIdx.x;
    const int row0 = blockIdx.x * 128;
    const int lane = tid & 63;
    const int wv   = tid >> 6;
    const int wvu  = __builtin_amdgcn_readfirstlane(wv);
    const int wm   = (wv & 1) * 64;          // wave row base
    const int wn   = (wv >> 1) * 128;        // wave col base
    const int l15  = lane & 15;
    const int lq   = lane >> 4;
    const int lr8  = lane >> 3;              // staging: row within 8-group
    const int lc8  = (lane & 7) * 8;         // staging: col (u16) within row

    if (MODE == 3) {
        const float p = ldv(extra, tid, f32);
        const float s = (p > 20.f) ? p : log1pf(expf(p));
        sscr[tid] = 1.0f / s;
    }

    f32x4 acc[4][8] = {};

    for (int k0 = 0; k0 < 256; k0 += 64) {
        // ---- B stage: wave w rows [w*64, w*64+64), 8 DMA instrs. ----------
        #pragma unroll
        for (int it = 0; it < 8; ++it) {
            const int r = wvu * 64 + it * 8 + lr8;
            gl16(BT + (size_t)r * 256 + k0 + swz(r, lc8),
                 &Bs[(wvu * 64 + it * 8) * 64]);
        }
        // ---- A stage ------------------------------------------------------
        if (MODE == 2 || abf || !f32) {
            const u16* Ab = (MODE == 2) ? Abf : (const u16*)Aany;
            #pragma unroll
            for (int it = 0; it < 4; ++it) {
                const int r = wvu * 32 + it * 8 + lr8;
                gl16(Ab + (size_t)(row0 + r) * 256 + k0 + swz(r, lc8),
                     &As[(wvu * 32 + it * 8) * 64]);
            }
        } else {
            const int sr = tid >> 1;              // row 0..127
            const int sk = (tid & 1) * 32;        // k-half
            const float* ag = (const float*)Aany +
                              (size_t)(row0 + sr) * 256 + k0 + sk;
            #pragma unroll
            for (int j = 0; j < 4; ++j) {
                const float4 f0 = *reinterpret_cast<const float4*>(ag + j * 8);
                const float4 f1 = *reinterpret_cast<const float4*>(ag + j * 8 + 4);
                *reinterpret_cast<uint4*>(
                    &As[sr * 64 + swz(sr, sk + j * 8)]) = pack8(f0, f1);
            }
        }
        __syncthreads();
        #pragma unroll
        for (int ks = 0; ks < 64; ks += 32) {
            const int ko = ks + lq * 8;
            short8 av[4], bv[8];
            #pragma unroll
            for (int i = 0; i < 4; ++i) {
                const int m = wm + i * 16 + l15;
                av[i] = *reinterpret_cast<const short8*>(&As[m * 64 + swz(m, ko)]);
            }
            #pragma unroll
            for (int j = 0; j < 8; ++j) {
                const int n = wn + j * 16 + l15;
                bv[j] = *reinterpret_cast<const short8*>(&Bs[n * 64 + swz(n, ko)]);
            }
            #pragma unroll
            for (int i = 0; i < 4; ++i)
                #pragma unroll
                for (int j = 0; j < 8; ++j)
                    acc[i][j] = __builtin_amdgcn_mfma_f32_16x16x32_bf16(
                        av[i], bv[j], acc[i][j], 0, 0, 0);
        }
        __syncthreads();
    }

    if (MODE == 3) {
        // focus: xv=(relu+eps)/softplus; per-row s2=sum xv^2, s6=sum xv^6.
        #pragma unroll
        for (int i = 0; i < 4; ++i) {
            #pragma unroll
            for (int rg = 0; rg < 4; ++rg) {
                const int lr = wm + i * 16 + lq * 4 + rg;   // local row 0..127
                float s2 = 0.f, s6 = 0.f;
                #pragma unroll
                for (int j = 0; j < 8; ++j) {
                    const int col = wn + j * 16 + l15;
                    const float xv =
                        (fmaxf(acc[i][j][rg], 0.f) + 1e-6f) * sscr[col];
                    acc[i][j][rg] = xv;
                    const float x2 = xv * xv;
                    s2 += x2;
                    s6 += x2 * x2 * x2;
                }
                #pragma unroll
                for (int off = 1; off < 16; off <<= 1) {
                    s2 += __shfl_xor(s2, off);
                    s6 += __shfl_xor(s6, off);
                }
                if (l15 == 0) { red2[wv >> 1][lr] = s2; red6[wv >> 1][lr] = s6; }
            }
        }
        __syncthreads();
        if (tid < 128)
            ratio_s[tid] = sqrtf((red2[0][tid] + red2[1][tid]) /
                                 (red6[0][tid] + red6[1][tid]));
        __syncthreads();
    }

    // Store. C/D layout: row=(lane>>4)*4+reg, col=lane&15 (m89-verified).
    #pragma unroll
    for (int i = 0; i < 4; ++i) {
        #pragma unroll
        for (int j = 0; j < 8; ++j) {
            const int gcol = wn + j * 16 + l15;
            #pragma unroll
            for (int rg = 0; rg < 4; ++rg) {
                const int lr = wm + i * 16 + lq * 4 + rg;
                const size_t oi = (size_t)(row0 + lr) * 256 + gcol;
                const float a = acc[i][j][rg];
                if (MODE == 0) {
                    O0[oi] = f2b(a);
                } else if (MODE == 3) {
                    O0[oi] = f2b(a * a * a * ratio_s[lr]);
                } else {
                    const float o = a + ldv(extra, gcol, f32);
                    if (f32) ((float*)O0)[oi] = o;
                    else     O0[oi] = f2b(o);
                }
            }
        }
    }
}

// ---------------------------------------------------------------------------
// Fused k-path v3 (chunk-merged): k = x @ Wkv[:, :256] + pe -> focus ->
// kvsum/ksum atomics. Both 64-row chunks in ONE K-loop sharing each B stage.
// ---------------------------------------------------------------------------
__global__ __launch_bounds__(256, 2)
void fusedk_kernel(const void* __restrict__ x, const u16* __restrict__ WkvT,
                   const u16* __restrict__ peb, const u16* __restrict__ v,
                   const void* __restrict__ sp,
                   float* __restrict__ kvsm, float* __restrict__ ksm,
                   const int* __restrict__ flagp, int abf)
{
    const int f32 = *flagp;
    __shared__ u16 smem[32768];          // 64 KB, phase-aliased
    __shared__ float red2[4][64];
    __shared__ float red6[4][64];
    __shared__ float ratio_s[64];
    __shared__ float sscr[256];
    u16* As  = smem;                     // [128][64]  (GEMM)
    u16* Bs  = smem + 8192;              // [256][64]  (GEMM)
    u16* KsT = smem;                     // [256][64]  (phase 2b/3)
    u16* VsT = smem + 16384;             // [256][64]  (phase 3)

    const int tid  = threadIdx.x;
    const int lane = tid & 63;
    const int wv   = tid >> 6;           // 0..3
    const int wvu  = __builtin_amdgcn_readfirstlane(wv);
    const int l15  = lane & 15;
    const int lq   = lane >> 4;
    const int wn   = wv * 64;
    const int lr8  = lane >> 3;
    const int lc8  = (lane & 7) * 8;

    {
        const float p = ldv(sp, tid, f32);
        const float s = (p > 20.f) ? p : log1pf(expf(p));
        sscr[tid] = 1.0f / s;
    }

    f32x4 cc[2][4] = {};                 // kvsum accum (2 heads/wave)
    float ksp[4] = {0.f, 0.f, 0.f, 0.f}; // ksum accum

    const int b    = blockIdx.x >> 5;    // batch (128 rows/block)
    const int row0 = blockIdx.x * 128;
    const int vr   = lane;               // V staging row
    const int veb  = wv * 64;            // V staging col base

    // ---- Phase 1: GEMM, both chunks, shared B staging. --------------------
    f32x4 acc[2][4][4] = {};
    for (int k0 = 0; k0 < 256; k0 += 64) {
        #pragma unroll
        for (int it = 0; it < 8; ++it) {
            const int r = wvu * 64 + it * 8 + lr8;
            gl16(WkvT + (size_t)r * 256 + k0 + swz(r, lc8),
                 &Bs[(wvu * 64 + it * 8) * 64]);
        }
        if (abf || !f32) {
            #pragma unroll
            for (int it = 0; it < 4; ++it) {
                const int r = wvu * 32 + it * 8 + lr8;
                gl16((const u16*)x + (size_t)(row0 + r) * 256 + k0 + swz(r, lc8),
                     &As[(wvu * 32 + it * 8) * 64]);
            }
        } else {
            const int sr = tid >> 1;              // row 0..127
            const int sk = (tid & 1) * 32;        // k-half
            const float* ag = (const float*)x +
                              (size_t)(row0 + sr) * 256 + k0 + sk;
            #pragma unroll
            for (int j = 0; j < 4; ++j) {
                const float4 f0 = *reinterpret_cast<const float4*>(ag + j * 8);
                const float4 f1 = *reinterpret_cast<const float4*>(ag + j * 8 + 4);
                *reinterpret_cast<uint4*>(
                    &As[sr * 64 + swz(sr, sk + j * 8)]) = pack8(f0, f1);
            }
        }
        __syncthreads();
        #pragma unroll
        for (int c = 0; c < 2; ++c) {
            #pragma unroll
            for (int ks = 0; ks < 64; ks += 32) {
                const int ko = ks + lq * 8;
                short8 av[4], bvv[4];
                #pragma unroll
                for (int i = 0; i < 4; ++i) {
                    const int m = c * 64 + i * 16 + l15;
                    av[i] = *reinterpret_cast<const short8*>(&As[m * 64 + swz(m, ko)]);
                }
                #pragma unroll
                for (int j = 0; j < 4; ++j) {
                    const int n = wn + j * 16 + l15;
                    bvv[j] = *reinterpret_cast<const short8*>(&Bs[n * 64 + swz(n, ko)]);
                }
                #pragma unroll
                for (int i = 0; i < 4; ++i)
                    #pragma unroll
                    for (int j = 0; j < 4; ++j)
                        acc[c][i][j] = __builtin_amdgcn_mfma_f32_16x16x32_bf16(
                            av[i], bvv[j], acc[c][i][j], 0, 0, 0);
            }
        }
        __syncthreads();
    }

    // ---- Phases 2-3 per chunk. --------------------------------------------
    #pragma unroll
    for (int c = 0; c < 2; ++c) {
        const int nb = (row0 & 4095) + c * 64;

        // Phase 2a: +peb, normalize, s2/s6 reduce.
        #pragma unroll
        for (int i = 0; i < 4; ++i) {
            #pragma unroll
            for (int rg = 0; rg < 4; ++rg) {
                const int lrow = i * 16 + lq * 4 + rg;
                float s2 = 0.f, s6 = 0.f;
                #pragma unroll
                for (int j = 0; j < 4; ++j) {
                    const int col = wn + j * 16 + l15;
                    const float t = acc[c][i][j][rg] +
                        b2f(peb[(size_t)(nb + lrow) * 256 + col]);
                    const float xv = (fmaxf(t, 0.f) + 1e-6f) * sscr[col];
                    acc[c][i][j][rg] = xv;
                    const float x2 = xv * xv;
                    s2 += x2;
                    s6 += x2 * x2 * x2;
                }
                #pragma unroll
                for (int off = 1; off < 16; off <<= 1) {
                    s2 += __shfl_xor(s2, off);
                    s6 += __shfl_xor(s6, off);
                }
                if (l15 == 0) { red2[wv][lrow] = s2; red6[wv][lrow] = s6; }
            }
        }
        __syncthreads();
        if (tid < 64) {
            const float s2t = red2[0][tid] + red2[1][tid] + red2[2][tid] + red2[3][tid];
            const float s6t = red6[0][tid] + red6[1][tid] + red6[2][tid] + red6[3][tid];
            ratio_s[tid] = sqrtf(s2t / s6t);
        }
        __syncthreads();

        // Phase 2b: finalize k -> KsT[d][r] (swz); ksum partials.
        {
            float kscol[4] = {0.f, 0.f, 0.f, 0.f};
            #pragma unroll
            for (int i = 0; i < 4; ++i)
                #pragma unroll
                for (int rg = 0; rg < 4; ++rg) {
                    const int lrow = i * 16 + lq * 4 + rg;
                    const float rt = ratio_s[lrow];
                    #pragma unroll
                    for (int j = 0; j < 4; ++j) {
                        const float xv = acc[c][i][j][rg];
                        const float kf = xv * xv * xv * rt;
                        const int d = wn + j * 16 + l15;
                        KsT[d * 64 + swz(d, lrow)] = f2b(kf);
                        kscol[j] += kf;
                    }
                }
            #pragma unroll
            for (int j = 0; j < 4; ++j) {
                float kp = kscol[j];
                kp += __shfl_xor(kp, 16);
                kp += __shfl_xor(kp, 32);
                ksp[j] += kp;
            }
        }

        // Stage V transposed: VsT[e][r] (swz).
        {
            const u16* vg = v + (size_t)(row0 + c * 64 + vr) * 256 + veb;
            uint4 t0[8];
            #pragma unroll
            for (int j = 0; j < 8; ++j)
                t0[j] = *reinterpret_cast<const uint4*>(vg + j * 8);
            #pragma unroll
            for (int j = 0; j < 8; ++j) {
                const u16* pp = (const u16*)&t0[j];
                #pragma unroll
                for (int m = 0; m < 8; ++m) {
                    const int e = veb + j * 8 + m;
                    VsT[e * 64 + swz(e, vr)] = pp[m];
                }
            }
        }
        __syncthreads();

        // Phase 3: kvsum += KsT^T VsT per head via MFMA (b128 frags).
        #pragma unroll
        for (int hh = 0; hh < 2; ++hh) {
            const int cb = (wv * 2 + hh) * 32;
            const int da = cb + l15, dbx = cb + 16 + l15;
            #pragma unroll
            for (int kk = 0; kk < 64; kk += 32) {
                const int ko = kk + lq * 8;
                const short8 a0 = *reinterpret_cast<const short8*>(
                    &KsT[da * 64 + swz(da, ko)]);
                const short8 a1 = *reinterpret_cast<const short8*>(
                    &KsT[dbx * 64 + swz(dbx, ko)]);
                const short8 b0 = *reinterpret_cast<const short8*>(
                    &VsT[da * 64 + swz(da, ko)]);
                const short8 b1 = *reinterpret_cast<const short8*>(
                    &VsT[dbx * 64 + swz(dbx, ko)]);
                cc[hh][0] = __builtin_amdgcn_mfma_f32_16x16x32_bf16(a0, b0, cc[hh][0], 0, 0, 0);
                cc[hh][1] = __builtin_amdgcn_mfma_f32_16x16x32_bf16(a0, b1, cc[hh][1], 0, 0, 0);
                cc[hh][2] = __builtin_amdgcn_mfma_f32_16x16x32_bf16(a1, b0, cc[hh][2], 0, 0, 0);
                cc[hh][3] = __builtin_amdgcn_mfma_f32_16x16x32_bf16(a1, b1, cc[hh][3], 0, 0, 0);
            }
        }
        __syncthreads();
    }

    // ---- Atomics once per block (2-slot hash halves contention). ----------
    const int slot = blockIdx.x & 1;
    float* ksb = ksm + (size_t)(slot * 16 + b) * 256;
    #pragma unroll
    for (int j = 0; j < 4; ++j)
        if (lane < 16)
            atomicAdd(&ksb[wn + j * 16 + lane], ksp[j]);
    #pragma unroll
    for (int hh = 0; hh < 2; ++hh) {
        const int h = wv * 2 + hh;
        float* base = kvsm + ((size_t)(slot * 16 + b) * 8 + h) * 1024;
        #pragma unroll
        for (int rg = 0; rg < 4; ++rg) {
            const int d0 = lq * 4 + rg;
            atomicAdd(&base[(size_t)d0 * 32 + l15],             cc[hh][0][rg]);
            atomicAdd(&base[(size_t)d0 * 32 + 16 + l15],        cc[hh][1][rg]);
            atomicAdd(&base[(size_t)(d0 + 16) * 32 + l15],      cc[hh][2][rg]);
            atomicAdd(&base[(size_t)(d0 + 16) * 32 + 16 + l15], cc[hh][3][rg]);
        }
    }
}

// ---------------------------------------------------------------------------
// attn v2 (MFMA) IN-PLACE on qy: out[t][h*32+e] = (q[t]·kvT[h][e]) / (zd+eps).
// Block = 64 rows of one batch, 4 waves x 16 rows. q staged via
// global_load_lds with XOR-swizzled source; kvT[h][e][d] bf16 (stride 40:
// bank-spread); 16 MFMA (16x16x32) per wave; zd computed ONCE per (row,head)
// in f32 (old numerics), broadcast via LDS.
// ---------------------------------------------------------------------------
__global__ __launch_bounds__(256, 2)
void attn_mfma_kernel(u16* __restrict__ qy, const float* __restrict__ kvsum,
                      const float* __restrict__ ksum)
{
    __shared__ u16 qs[64 * 256];         // swizzled rows (32 KB)
    __shared__ u16 kvT[8 * 32 * 40];     // [h][e][d], stride 40 (20 KB)
    __shared__ float km[8][32];
    __shared__ float zds[64][8];
    const int tid  = threadIdx.x;
    const int lane = tid & 63;
    const int wv   = tid >> 6;
    const int wvu  = __builtin_amdgcn_readfirstlane(wv);
    const int l15  = lane & 15;
    const int lq   = lane >> 4;
    const int b    = blockIdx.x >> 6;        // 64 blocks per batch
    const int n0   = (blockIdx.x & 63) * 64; // row base within batch
    const float inv_n = 1.0f / 4096.0f;

    // ---- Stage q rows via DMA (src pre-swizzled per row). -----------------
    {
        const int qr2 = lane >> 5;           // row within 2-row DMA group
        const int qc8 = (lane & 31) * 8;     // col (u16)
        const u16* qb = qy + (size_t)(b * 4096 + n0) * 256;
        #pragma unroll
        for (int it = 0; it < 8; ++it) {
            const int r = wvu * 16 + it * 2 + qr2;
            gl16(qb + (size_t)r * 256 + (qc8 ^ ((r & 7) << 3)),
                 &qs[(wvu * 16 + it * 2) * 256]);
        }
    }
    // ---- kvT + km staging. ------------------------------------------------
    {
        const int h = tid >> 5, e = tid & 31;
        const float* k0 = kvsum + (size_t)b * 8192 + h * 1024 + e;
        const float* k1 = kvsum + (size_t)(16 + b) * 8192 + h * 1024 + e;
        #pragma unroll
        for (int d = 0; d < 32; ++d)
            kvT[h * 1280 + e * 40 + d] = f2b((k0[d * 32] + k1[d * 32]) * inv_n);
        (&km[0][0])[tid] = (ksum[(size_t)b * 256 + tid] +
                            ksum[(size_t)(16 + b) * 256 + tid]) * inv_n;
    }
    __syncthreads();

    // ---- zd: once per (row, head); wave w handles heads 2w, 2w+1. ---------
    {
        const int zt = tid & 63;
        const int zh0 = (tid >> 6) * 2;
        #pragma unroll
        for (int hh = 0; hh < 2; ++hh) {
            const int h = zh0 + hh;
            float s = 0.f;
            #pragma unroll
            for (int d = 0; d < 32; ++d) {
                const int col = (h * 32 + d) ^ ((zt & 7) << 3);
                s = fmaf(b2f(qs[zt * 256 + col]), km[h][d], s);
            }
            zds[zt][h] = s;
        }
    }

    // ---- MFMA: wave rows [wvu*16, wvu*16+16), all 8 heads x 2 e-halves. ---
    f32x4 acc[8][2];
    #pragma unroll
    for (int h = 0; h < 8; ++h) {
        const int m = wvu * 16 + l15;
        const int col = (h * 32 + lq * 8) ^ ((m & 7) << 3);
        const short8 av = *reinterpret_cast<const short8*>(&qs[m * 256 + col]);
        const short8 b0 = *reinterpret_cast<const short8*>(
            &kvT[h * 1280 + l15 * 40 + lq * 8]);
        const short8 b1 = *reinterpret_cast<const short8*>(
            &kvT[h * 1280 + (16 + l15) * 40 + lq * 8]);
        const f32x4 z = {0.f, 0.f, 0.f, 0.f};
        acc[h][0] = __builtin_amdgcn_mfma_f32_16x16x32_bf16(av, b0, z, 0, 0, 0);
        acc[h][1] = __builtin_amdgcn_mfma_f32_16x16x32_bf16(av, b1, z, 0, 0, 0);
    }
    __syncthreads();

    // ---- Epilogue: divide by zd (broadcast read) and store. ---------------
    u16* qb = qy + (size_t)(b * 4096 + n0) * 256;
    #pragma unroll
    for (int h = 0; h < 8; ++h) {
        #pragma unroll
        for (int eh = 0; eh < 2; ++eh) {
            const int gcol = h * 32 + eh * 16 + l15;
            #pragma unroll
            for (int rg = 0; rg < 4; ++rg) {
                const int lr = wvu * 16 + lq * 4 + rg;
                const float z = 1.0f / (zds[lr][h] + 1e-6f);
                qb[(size_t)lr * 256 + gcol] = f2b(acc[h][eh][rg] * z);
            }
        }
    }
}

// ---------------------------------------------------------------------------
// Depthwise 5x5 conv: LDS-staged 12x12x256 halo tile, thread=channel,
// register sliding 5x12 window, 8x8 outputs/thread, += into y with bias.
// ---------------------------------------------------------------------------
__global__ __launch_bounds__(256, 2)
void conv_add_kernel(const u16* __restrict__ v, const void* __restrict__ w,
                     const void* __restrict__ bias, u16* __restrict__ y,
                     const int* __restrict__ flagp)
{
    const int f32 = *flagp;
    __shared__ u16 vt[144 * 256];   // [py*12+px][ch], 73728 B
    __shared__ float wl[800];
    __shared__ float bl[32];
    const int tid = threadIdx.x;
    for (int i = tid; i < 800; i += 256) wl[i] = ldv(w, i, f32);
    if (tid < 32) bl[tid] = ldv(bias, tid, f32);

    const int bb = blockIdx.x >> 6;
    const int ty = (blockIdx.x >> 3) & 7;
    const int tx = blockIdx.x & 7;
    const int y0 = ty * 8, x0 = tx * 8;
    const u16* vb = v + (size_t)bb * 4096 * 256;

    #pragma unroll
    for (int it = 0; it < 18; ++it) {
        const int idx = it * 256 + tid;       // 0..4607
        const int px  = idx >> 5;             // 0..143
        const int c8  = (idx & 31) * 8;
        const int py  = px / 12, pxx = px - py * 12;
        const int yy = y0 + py - 2, xx = x0 + pxx - 2;
        uint4 val = {0u, 0u, 0u, 0u};
        if (yy >= 0 && yy < 64 && xx >= 0 && xx < 64)
            val = *reinterpret_cast<const uint4*>(
                vb + (size_t)((yy << 6) + xx) * 256 + c8);
        *reinterpret_cast<uint4*>(&vt[px * 256 + c8]) = val;
    }
    __syncthreads();

    const int c  = tid;            // channel
    const int dc = c & 31;
    float wreg[25];
    #pragma unroll
    for (int i = 0; i < 25; ++i) wreg[i] = wl[dc * 25 + i];
    const float bv = bl[dc];

    float win[5][12];
    #pragma unroll
    for (int r = 0; r < 5; ++r)
        #pragma unroll
        for (int cc = 0; cc < 12; ++cc)
            win[r][cc] = b2f(vt[(r * 12 + cc) * 256 + c]);

    u16* yb = y + ((size_t)bb * 4096 + (size_t)y0 * 64 + x0) * 256 + c;
    #pragma unroll
    for (int oy = 0; oy < 8; ++oy) {
        if (oy) {
            #pragma unroll
            for (int r = 0; r < 4; ++r)
                #pragma unroll
                for (int cc = 0; cc < 12; ++cc) win[r][cc] = win[r + 1][cc];
            #pragma unroll
            for (int cc = 0; cc < 12; ++cc)
                win[4][cc] = b2f(vt[((oy + 4) * 12 + cc) * 256 + c]);
        }
        #pragma unroll
        for (int ox = 0; ox < 8; ++ox) {
            float s = 0.f;
            #pragma unroll
            for (int ky = 0; ky < 5; ++ky)
                #pragma unroll
                for (int kx = 0; kx < 5; ++kx)
                    s = fmaf(win[ky][ox + kx], wreg[ky * 5 + kx], s);
            u16* yp = yb + (size_t)(oy * 64 + ox) * 256;
            *yp = f2b(b2f(*yp) + s + bv);
        }
    }
}

// ---------------------------------------------------------------------------
extern "C" void kernel_launch(void* const* d_in, const int* in_sizes, int n_in,
                              void* d_out, int out_size, void* d_ws, size_t ws_size,
                              hipStream_t stream)
{
    (void)in_sizes; (void)n_in; (void)out_size;
    const void* x   = d_in[0];
    const void* Wq  = d_in[1];
    const void* Wkv = d_in[2];
    const void* Wp  = d_in[3];
    const void* bp  = d_in[4];
    const void* sp  = d_in[5];
    const void* pe  = d_in[6];
    const void* dw  = d_in[7];
    const void* db  = d_in[8];

    // ws layout:
    // [flag 64B][kvsm 1M (2 slots)][ksm 32K (2 slots)][WqT 128K][WkvT 256K]
    // [WpT 128K][peb 2M][qy 32M][xb 32M (only if ws large enough)]
    int*   flag = (int*)d_ws;
    float* kvsm = (float*)((char*)d_ws + 64);
    float* ksm  = kvsm + 262144;
    u16*   WqT  = (u16*)(ksm + 8192);
    u16*   WkvT = WqT + 65536;
    u16*   WpT  = WkvT + 131072;
    u16*   peb  = WpT + 65536;
    u16*   qy   = peb + 1048576;
    u16*   xb   = qy + (size_t)16777216;
    // v (bf16, 33.5 MB) parked at the START of d_out (dead before the final
    // GEMM overwrites d_out).
    u16*   v    = (u16*)d_out;

    const size_t need = (size_t)((char*)(xb + 16777216) - (char*)d_ws);
    const int big = (ws_size >= need) ? 1 : 0;

    hipMemsetAsync(kvsm, 0, (262144 + 8192) * sizeof(float), stream);
    detect_kernel<<<1, 64, 0, stream>>>(x, flag);
    if (big) xcvt_kernel<<<8192, 256, 0, stream>>>(x, xb, flag);
    pecvt_kernel<<<1024, 256, 0, stream>>>(pe, peb, flag);
    wtrans_kernel<<<64, 256, 0, stream>>>(Wq, WqT, 256, flag);
    wtrans_kernel<<<128, 256, 0, stream>>>(Wkv, WkvT, 512, flag);
    wtrans_kernel<<<64, 256, 0, stream>>>(Wp, WpT, 256, flag);

    const void* Ax = big ? (const void*)xb : x;

    // q = focus(x @ Wq)
    hipLaunchKernelGGL((gemm256<3>), dim3(512), dim3(256), 0, stream,
                       Ax, (const u16*)nullptr, WqT, qy, sp, flag, big);
    // v = x @ Wkv[:, 256:]
    hipLaunchKernelGGL((gemm256<0>), dim3(512), dim3(256), 0, stream,
                       Ax, (const u16*)nullptr, WkvT + (size_t)256 * 256, v,
                       (const void*)nullptr, flag, big);
    // fused k path: gemm + pe + focus + kvsum/ksum (k never materialized)
    fusedk_kernel<<<512, 256, 0, stream>>>(Ax, WkvT, peb, v, sp, kvsm, ksm,
                                           flag, big);

    attn_mfma_kernel<<<1024, 256, 0, stream>>>(qy, kvsm, ksm);
    conv_add_kernel<<<1024, 256, 0, stream>>>(v, dw, db, qy, flag);
    hipLaunchKernelGGL((gemm256<2>), dim3(512), dim3(256), 0, stream,
                       (const void*)nullptr, qy, WpT, (u16*)d_out, bp, flag, 0);
}

// Round 7
// 312.167 us; speedup vs baseline: 1.4562x; 1.0428x over previous
//
#include <hip/hip_runtime.h>
#include <hip/hip_bf16.h>

typedef unsigned short u16;
using bf16_t = __hip_bfloat16;
typedef short short8 __attribute__((ext_vector_type(8)));
typedef float f32x4 __attribute__((ext_vector_type(4)));

__device__ __forceinline__ float b2f(u16 u) {
    return __uint_as_float((unsigned int)u << 16);
}
__device__ __forceinline__ u16 f2b(float f) {
    bf16_t h = __float2bfloat16(f);
    union { bf16_t h; u16 u; } cv; cv.h = h; return cv.u;
}
__device__ __forceinline__ float ldv(const void* p, size_t i, int f32) {
    return f32 ? ((const float*)p)[i] : b2f(((const u16*)p)[i]);
}
__device__ __forceinline__ uint4 pack8(float4 a, float4 b) {
    uint4 u;
    u.x = (unsigned)f2b(a.x) | ((unsigned)f2b(a.y) << 16);
    u.y = (unsigned)f2b(a.z) | ((unsigned)f2b(a.w) << 16);
    u.z = (unsigned)f2b(b.x) | ((unsigned)f2b(b.y) << 16);
    u.w = (unsigned)f2b(b.z) | ((unsigned)f2b(b.w) << 16);
    return u;
}
// XOR swizzle for stride-64(u16) LDS tiles: element (n,k) lives at
// n*64 + (k ^ ((n&7)<<3)). Bijective within each row; 16B blocks preserved.
__device__ __forceinline__ int swz(int n, int k) {
    return k ^ ((n & 7) << 3);
}
// Async global->LDS DMA, 16B per lane. LDS dest must be wave-uniform base;
// HW writes lane i at base + i*16B. Global src is per-lane (pre-swizzled).
__device__ __forceinline__ void gl16(const u16* g, u16* l) {
    __builtin_amdgcn_global_load_lds(
        (const __attribute__((address_space(1))) unsigned int*)g,
        (__attribute__((address_space(3))) unsigned int*)l, 16, 0, 0);
}

// ---------------------------------------------------------------------------
// Input-dtype detector (flag=1 -> fp32 inputs & fp32 output).
// ---------------------------------------------------------------------------
__global__ void detect_kernel(const void* __restrict__ x, int* __restrict__ flag)
{
    const int t = threadIdx.x;
    const u16 h = ((const u16*)x)[2 * t];
    const int e = (h >> 7) & 0xFF;
    const int plaus = (e >= 112 && e <= 133) ? 1 : 0;
    const unsigned long long m = __ballot(plaus);
    if (t == 0) flag[0] = (__popcll(m) < 32) ? 1 : 0;
}

// x -> xb (bf16 always). 8 elements/thread.
__global__ __launch_bounds__(256)
void xcvt_kernel(const void* __restrict__ x, u16* __restrict__ xb,
                 const int* __restrict__ flagp)
{
    const size_t i = ((size_t)blockIdx.x * 256 + threadIdx.x) * 8;
    if (*flagp) {
        const float* xf = (const float*)x + i;
        const float4 f0 = *reinterpret_cast<const float4*>(xf);
        const float4 f1 = *reinterpret_cast<const float4*>(xf + 4);
        *reinterpret_cast<uint4*>(xb + i) = pack8(f0, f1);
    } else {
        *reinterpret_cast<uint4*>(xb + i) =
            *reinterpret_cast<const uint4*>((const u16*)x + i);
    }
}

// ---------------------------------------------------------------------------
// Merged preprocessing: blocks [0,1024): pe->peb; blocks [1024,1280):
// W->WT LDS-tiled transpose (Wq 64, Wkv 128, Wp 64 tiles).
// ---------------------------------------------------------------------------
__global__ __launch_bounds__(256)
void prep_kernel(const void* __restrict__ pe, u16* __restrict__ peb,
                 const void* __restrict__ Wq, u16* __restrict__ WqT,
                 const void* __restrict__ Wkv, u16* __restrict__ WkvT,
                 const void* __restrict__ Wp, u16* __restrict__ WpT,
                 const int* __restrict__ flagp)
{
    const int f32 = *flagp;
    __shared__ float tile[32][33];
    const int bid = blockIdx.x;
    if (bid < 1024) {
        const size_t i = ((size_t)bid * 256 + threadIdx.x) * 4;
        if (f32) {
            const float4 f = *reinterpret_cast<const float4*>((const float*)pe + i);
            ushort4 o; o.x = f2b(f.x); o.y = f2b(f.y); o.z = f2b(f.z); o.w = f2b(f.w);
            *reinterpret_cast<ushort4*>(peb + i) = o;
        } else {
            *reinterpret_cast<ushort4*>(peb + i) =
                *reinterpret_cast<const ushort4*>((const u16*)pe + i);
        }
        return;
    }
    int lb = bid - 1024;
    const void* W; u16* WT; int N;
    if (lb < 64)       { W = Wq;  WT = WqT;  N = 256; }
    else if (lb < 192) { W = Wkv; WT = WkvT; N = 512; lb -= 64; }
    else               { W = Wp;  WT = WpT;  N = 256; lb -= 192; }
    const int tx = threadIdx.x & 31, ty = threadIdx.x >> 5;   // ty 0..7
    const int bx = lb % (N >> 5);   // n tile
    const int by = lb / (N >> 5);   // k tile
    #pragma unroll
    for (int r = 0; r < 4; ++r) {
        const int k = by * 32 + ty + r * 8;
        const int n = bx * 32 + tx;
        tile[ty + r * 8][tx] = ldv(W, (size_t)k * N + n, f32);
    }
    __syncthreads();
    #pragma unroll
    for (int r = 0; r < 4; ++r) {
        const int n2 = bx * 32 + ty + r * 8;
        const int k2 = by * 32 + tx;
        WT[(size_t)n2 * 256 + k2] = f2b(tile[tx][ty + r * 8]);
    }
}

// ---------------------------------------------------------------------------
// MFMA GEMM, BN=256: O[rows x 256] = A[rows x 256] @ B. 128x256 block tile,
// BK=64, 4 waves 2(m)x2(n), wave tile 64x128 (acc[4][8]).
// MODE 0: O0(bf16) = A@B                      (v-gemm)
// MODE 2: out = A@B + bias; fp32/bf16 store   (A = qy bf16)
// MODE 3: O0(bf16) = focus(A@B)               (q-gemm, focus fused)
// ---------------------------------------------------------------------------
template<int MODE>
__global__ __launch_bounds__(256, 2)
void gemm256(const void* __restrict__ Aany, const u16* __restrict__ Abf,
             const u16* __restrict__ BT, u16* __restrict__ O0,
             const void* __restrict__ extra, const int* __restrict__ flagp,
             int abf)
{
    const int f32 = *flagp;
    __shared__ u16 As[128 * 64];     // linear, swizzled content
    __shared__ u16 Bs[256 * 64];
    __shared__ float red2[2][128];
    __shared__ float red6[2][128];
    __shared__ float ratio_s[128];
    __shared__ float sscr[256];

    const int tid  = threadIdx.x;
    const int row0 = blockIdx.x * 128;
    const int lane = tid & 63;
    const int wv   = tid >> 6;
    const int wvu  = __builtin_amdgcn_readfirstlane(wv);
    const int wm   = (wv & 1) * 64;          // wave row base
    const int wn   = (wv >> 1) * 128;        // wave col base
    const int l15  = lane & 15;
    const int lq   = lane >> 4;
    const int lr8  = lane >> 3;              // staging: row within 8-group
    const int lc8  = (lane & 7) * 8;         // staging: col (u16) within row

    if (MODE == 3) {
        const float p = ldv(extra, tid, f32);
        const float s = (p > 20.f) ? p : log1pf(expf(p));
        sscr[tid] = 1.0f / s;
    }

    f32x4 acc[4][8] = {};

    for (int k0 = 0; k0 < 256; k0 += 64) {
        // ---- B stage: wave w rows [w*64, w*64+64), 8 DMA instrs. ----------
        #pragma unroll
        for (int it = 0; it < 8; ++it) {
            const int r = wvu * 64 + it * 8 + lr8;
            gl16(BT + (size_t)r * 256 + k0 + swz(r, lc8),
                 &Bs[(wvu * 64 + it * 8) * 64]);
        }
        // ---- A stage ------------------------------------------------------
        if (MODE == 2 || abf || !f32) {
            const u16* Ab = (MODE == 2) ? Abf : (const u16*)Aany;
            #pragma unroll
            for (int it = 0; it < 4; ++it) {
                const int r = wvu * 32 + it * 8 + lr8;
                gl16(Ab + (size_t)(row0 + r) * 256 + k0 + swz(r, lc8),
                     &As[(wvu * 32 + it * 8) * 64]);
            }
        } else {
            const int sr = tid >> 1;              // row 0..127
            const int sk = (tid & 1) * 32;        // k-half
            const float* ag = (const float*)Aany +
                              (size_t)(row0 + sr) * 256 + k0 + sk;
            #pragma unroll
            for (int j = 0; j < 4; ++j) {
                const float4 f0 = *reinterpret_cast<const float4*>(ag + j * 8);
                const float4 f1 = *reinterpret_cast<const float4*>(ag + j * 8 + 4);
                *reinterpret_cast<uint4*>(
                    &As[sr * 64 + swz(sr, sk + j * 8)]) = pack8(f0, f1);
            }
        }
        __syncthreads();
        #pragma unroll
        for (int ks = 0; ks < 64; ks += 32) {
            const int ko = ks + lq * 8;
            short8 av[4], bv[8];
            #pragma unroll
            for (int i = 0; i < 4; ++i) {
                const int m = wm + i * 16 + l15;
                av[i] = *reinterpret_cast<const short8*>(&As[m * 64 + swz(m, ko)]);
            }
            #pragma unroll
            for (int j = 0; j < 8; ++j) {
                const int n = wn + j * 16 + l15;
                bv[j] = *reinterpret_cast<const short8*>(&Bs[n * 64 + swz(n, ko)]);
            }
            #pragma unroll
            for (int i = 0; i < 4; ++i)
                #pragma unroll
                for (int j = 0; j < 8; ++j)
                    acc[i][j] = __builtin_amdgcn_mfma_f32_16x16x32_bf16(
                        av[i], bv[j], acc[i][j], 0, 0, 0);
        }
        __syncthreads();
    }

    if (MODE == 3) {
        // focus: xv=(relu+eps)/softplus; per-row s2=sum xv^2, s6=sum xv^6.
        #pragma unroll
        for (int i = 0; i < 4; ++i) {
            #pragma unroll
            for (int rg = 0; rg < 4; ++rg) {
                const int lr = wm + i * 16 + lq * 4 + rg;   // local row 0..127
                float s2 = 0.f, s6 = 0.f;
                #pragma unroll
                for (int j = 0; j < 8; ++j) {
                    const int col = wn + j * 16 + l15;
                    const float xv =
                        (fmaxf(acc[i][j][rg], 0.f) + 1e-6f) * sscr[col];
                    acc[i][j][rg] = xv;
                    const float x2 = xv * xv;
                    s2 += x2;
                    s6 += x2 * x2 * x2;
                }
                #pragma unroll
                for (int off = 1; off < 16; off <<= 1) {
                    s2 += __shfl_xor(s2, off);
                    s6 += __shfl_xor(s6, off);
                }
                if (l15 == 0) { red2[wv >> 1][lr] = s2; red6[wv >> 1][lr] = s6; }
            }
        }
        __syncthreads();
        if (tid < 128)
            ratio_s[tid] = sqrtf((red2[0][tid] + red2[1][tid]) /
                                 (red6[0][tid] + red6[1][tid]));
        __syncthreads();
    }

    // Store. C/D layout: row=(lane>>4)*4+reg, col=lane&15 (m89-verified).
    #pragma unroll
    for (int i = 0; i < 4; ++i) {
        #pragma unroll
        for (int j = 0; j < 8; ++j) {
            const int gcol = wn + j * 16 + l15;
            #pragma unroll
            for (int rg = 0; rg < 4; ++rg) {
                const int lr = wm + i * 16 + lq * 4 + rg;
                const size_t oi = (size_t)(row0 + lr) * 256 + gcol;
                const float a = acc[i][j][rg];
                if (MODE == 0) {
                    O0[oi] = f2b(a);
                } else if (MODE == 3) {
                    O0[oi] = f2b(a * a * a * ratio_s[lr]);
                } else {
                    const float o = a + ldv(extra, gcol, f32);
                    if (f32) ((float*)O0)[oi] = o;
                    else     O0[oi] = f2b(o);
                }
            }
        }
    }
}

// ---------------------------------------------------------------------------
// Fused k-path v4: k = x @ Wkv[:, :256] + pe -> focus -> kvsum/ksum atomics.
// Chunk-merged GEMM (both 64-row chunks per K-step, shared B stage).
// Phase 3 split into 2 passes with HALF-size VsT[128][64]: pass p stages
// V cols [128p,128p+128), wave w computes head 4p+w (8 MFMA/pass).
// LDS: GEMM {As 16K | Bs 32K} / phase23 {KsT 32K | VsT 16K} = 48K (+3.3K
// reductions) ~= 52K -> 3 blocks/CU (was 69K -> 2). Occupancy-bound fix.
// ---------------------------------------------------------------------------
__global__ __launch_bounds__(256, 2)
void fusedk_kernel(const void* __restrict__ x, const u16* __restrict__ WkvT,
                   const u16* __restrict__ peb, const u16* __restrict__ v,
                   const void* __restrict__ sp,
                   float* __restrict__ kvsm, float* __restrict__ ksm,
                   const int* __restrict__ flagp, int abf)
{
    const int f32 = *flagp;
    __shared__ u16 smem[24576];          // 48 KB, phase-aliased
    __shared__ float red2[4][64];
    __shared__ float red6[4][64];
    __shared__ float ratio_s[64];
    __shared__ float sscr[256];
    u16* As  = smem;                     // [128][64]  (GEMM)
    u16* Bs  = smem + 8192;              // [256][64]  (GEMM)
    u16* KsT = smem;                     // [256][64]  (phase 2b/3)
    u16* VsT = smem + 16384;             // [128][64]  (phase 3, per pass)

    const int tid  = threadIdx.x;
    const int lane = tid & 63;
    const int wv   = tid >> 6;           // 0..3
    const int wvu  = __builtin_amdgcn_readfirstlane(wv);
    const int l15  = lane & 15;
    const int lq   = lane >> 4;
    const int wn   = wv * 64;
    const int lr8  = lane >> 3;
    const int lc8  = (lane & 7) * 8;

    {
        const float p = ldv(sp, tid, f32);
        const float s = (p > 20.f) ? p : log1pf(expf(p));
        sscr[tid] = 1.0f / s;
    }

    f32x4 cc[2][4] = {};                 // kvsum accum; cc[p] = head 4p+wv
    float ksp[4] = {0.f, 0.f, 0.f, 0.f}; // ksum accum

    const int b    = blockIdx.x >> 5;    // batch (128 rows/block)
    const int row0 = blockIdx.x * 128;

    // ---- Phase 1: GEMM, both chunks, shared B staging. --------------------
    f32x4 acc[2][4][4] = {};
    for (int k0 = 0; k0 < 256; k0 += 64) {
        #pragma unroll
        for (int it = 0; it < 8; ++it) {
            const int r = wvu * 64 + it * 8 + lr8;
            gl16(WkvT + (size_t)r * 256 + k0 + swz(r, lc8),
                 &Bs[(wvu * 64 + it * 8) * 64]);
        }
        if (abf || !f32) {
            #pragma unroll
            for (int it = 0; it < 4; ++it) {
                const int r = wvu * 32 + it * 8 + lr8;
                gl16((const u16*)x + (size_t)(row0 + r) * 256 + k0 + swz(r, lc8),
                     &As[(wvu * 32 + it * 8) * 64]);
            }
        } else {
            const int sr = tid >> 1;              // row 0..127
            const int sk = (tid & 1) * 32;        // k-half
            const float* ag = (const float*)x +
                              (size_t)(row0 + sr) * 256 + k0 + sk;
            #pragma unroll
            for (int j = 0; j < 4; ++j) {
                const float4 f0 = *reinterpret_cast<const float4*>(ag + j * 8);
                const float4 f1 = *reinterpret_cast<const float4*>(ag + j * 8 + 4);
                *reinterpret_cast<uint4*>(
                    &As[sr * 64 + swz(sr, sk + j * 8)]) = pack8(f0, f1);
            }
        }
        __syncthreads();
        #pragma unroll
        for (int c = 0; c < 2; ++c) {
            #pragma unroll
            for (int ks = 0; ks < 64; ks += 32) {
                const int ko = ks + lq * 8;
                short8 av[4], bvv[4];
                #pragma unroll
                for (int i = 0; i < 4; ++i) {
                    const int m = c * 64 + i * 16 + l15;
                    av[i] = *reinterpret_cast<const short8*>(&As[m * 64 + swz(m, ko)]);
                }
                #pragma unroll
                for (int j = 0; j < 4; ++j) {
                    const int n = wn + j * 16 + l15;
                    bvv[j] = *reinterpret_cast<const short8*>(&Bs[n * 64 + swz(n, ko)]);
                }
                #pragma unroll
                for (int i = 0; i < 4; ++i)
                    #pragma unroll
                    for (int j = 0; j < 4; ++j)
                        acc[c][i][j] = __builtin_amdgcn_mfma_f32_16x16x32_bf16(
                            av[i], bvv[j], acc[c][i][j], 0, 0, 0);
            }
        }
        __syncthreads();
    }

    // ---- Phases 2-3 per chunk. --------------------------------------------
    #pragma unroll
    for (int c = 0; c < 2; ++c) {
        const int nb = (row0 & 4095) + c * 64;

        // Phase 2a: +peb, normalize, s2/s6 reduce.
        #pragma unroll
        for (int i = 0; i < 4; ++i) {
            #pragma unroll
            for (int rg = 0; rg < 4; ++rg) {
                const int lrow = i * 16 + lq * 4 + rg;
                float s2 = 0.f, s6 = 0.f;
                #pragma unroll
                for (int j = 0; j < 4; ++j) {
                    const int col = wn + j * 16 + l15;
                    const float t = acc[c][i][j][rg] +
                        b2f(peb[(size_t)(nb + lrow) * 256 + col]);
                    const float xv = (fmaxf(t, 0.f) + 1e-6f) * sscr[col];
                    acc[c][i][j][rg] = xv;
                    const float x2 = xv * xv;
                    s2 += x2;
                    s6 += x2 * x2 * x2;
                }
                #pragma unroll
                for (int off = 1; off < 16; off <<= 1) {
                    s2 += __shfl_xor(s2, off);
                    s6 += __shfl_xor(s6, off);
                }
                if (l15 == 0) { red2[wv][lrow] = s2; red6[wv][lrow] = s6; }
            }
        }
        __syncthreads();
        if (tid < 64) {
            const float s2t = red2[0][tid] + red2[1][tid] + red2[2][tid] + red2[3][tid];
            const float s6t = red6[0][tid] + red6[1][tid] + red6[2][tid] + red6[3][tid];
            ratio_s[tid] = sqrtf(s2t / s6t);
        }
        __syncthreads();

        // Phase 2b: finalize k -> KsT[d][r] (swz); ksum partials.
        {
            float kscol[4] = {0.f, 0.f, 0.f, 0.f};
            #pragma unroll
            for (int i = 0; i < 4; ++i)
                #pragma unroll
                for (int rg = 0; rg < 4; ++rg) {
                    const int lrow = i * 16 + lq * 4 + rg;
                    const float rt = ratio_s[lrow];
                    #pragma unroll
                    for (int j = 0; j < 4; ++j) {
                        const float xv = acc[c][i][j][rg];
                        const float kf = xv * xv * xv * rt;
                        const int d = wn + j * 16 + l15;
                        KsT[d * 64 + swz(d, lrow)] = f2b(kf);
                        kscol[j] += kf;
                    }
                }
            #pragma unroll
            for (int j = 0; j < 4; ++j) {
                float kp = kscol[j];
                kp += __shfl_xor(kp, 16);
                kp += __shfl_xor(kp, 32);
                ksp[j] += kp;
            }
        }

        // Phase 3: two passes; pass p covers e in [128p, 128p+128).
        #pragma unroll
        for (int p = 0; p < 2; ++p) {
            // Stage VsT[e_local][r] (swz): thread row=lane, cols wv*32..+31.
            {
                const u16* vg = v + (size_t)(row0 + c * 64 + lane) * 256 +
                                p * 128 + wv * 32;
                uint4 t0[4];
                #pragma unroll
                for (int j = 0; j < 4; ++j)
                    t0[j] = *reinterpret_cast<const uint4*>(vg + j * 8);
                #pragma unroll
                for (int j = 0; j < 4; ++j) {
                    const u16* pp = (const u16*)&t0[j];
                    #pragma unroll
                    for (int m = 0; m < 8; ++m) {
                        const int el = wv * 32 + j * 8 + m;   // 0..127
                        VsT[el * 64 + swz(el, lane)] = pp[m];
                    }
                }
            }
            __syncthreads();
            // Wave wv computes head h = 4p + wv.
            {
                const int h  = p * 4 + wv;
                const int cb = h * 32;        // d-base in KsT
                const int el = wv * 32;       // e-local base in VsT
                #pragma unroll
                for (int kk = 0; kk < 64; kk += 32) {
                    const int ko = kk + lq * 8;
                    const short8 a0 = *reinterpret_cast<const short8*>(
                        &KsT[(cb + l15) * 64 + swz(cb + l15, ko)]);
                    const short8 a1 = *reinterpret_cast<const short8*>(
                        &KsT[(cb + 16 + l15) * 64 + swz(cb + 16 + l15, ko)]);
                    const short8 b0 = *reinterpret_cast<const short8*>(
                        &VsT[(el + l15) * 64 + swz(el + l15, ko)]);
                    const short8 b1 = *reinterpret_cast<const short8*>(
                        &VsT[(el + 16 + l15) * 64 + swz(el + 16 + l15, ko)]);
                    cc[p][0] = __builtin_amdgcn_mfma_f32_16x16x32_bf16(a0, b0, cc[p][0], 0, 0, 0);
                    cc[p][1] = __builtin_amdgcn_mfma_f32_16x16x32_bf16(a0, b1, cc[p][1], 0, 0, 0);
                    cc[p][2] = __builtin_amdgcn_mfma_f32_16x16x32_bf16(a1, b0, cc[p][2], 0, 0, 0);
                    cc[p][3] = __builtin_amdgcn_mfma_f32_16x16x32_bf16(a1, b1, cc[p][3], 0, 0, 0);
                }
            }
            __syncthreads();
        }
    }

    // ---- Atomics once per block (2-slot hash halves contention). ----------
    const int slot = blockIdx.x & 1;
    float* ksb = ksm + (size_t)(slot * 16 + b) * 256;
    #pragma unroll
    for (int j = 0; j < 4; ++j)
        if (lane < 16)
            atomicAdd(&ksb[wn + j * 16 + lane], ksp[j]);
    #pragma unroll
    for (int hh = 0; hh < 2; ++hh) {
        const int h = hh * 4 + wv;       // cc[hh] holds head 4*hh+wv
        float* base = kvsm + ((size_t)(slot * 16 + b) * 8 + h) * 1024;
        #pragma unroll
        for (int rg = 0; rg < 4; ++rg) {
            const int d0 = lq * 4 + rg;
            atomicAdd(&base[(size_t)d0 * 32 + l15],             cc[hh][0][rg]);
            atomicAdd(&base[(size_t)d0 * 32 + 16 + l15],        cc[hh][1][rg]);
            atomicAdd(&base[(size_t)(d0 + 16) * 32 + l15],      cc[hh][2][rg]);
            atomicAdd(&base[(size_t)(d0 + 16) * 32 + 16 + l15], cc[hh][3][rg]);
        }
    }
}

// ---------------------------------------------------------------------------
// attn (MFMA) IN-PLACE on qy: out[t][h*32+e] = (q[t]·kvT[h][e]) / (zd+eps).
// ---------------------------------------------------------------------------
__global__ __launch_bounds__(256, 2)
void attn_mfma_kernel(u16* __restrict__ qy, const float* __restrict__ kvsum,
                      const float* __restrict__ ksum)
{
    __shared__ u16 qs[64 * 256];         // swizzled rows (32 KB)
    __shared__ u16 kvT[8 * 32 * 40];     // [h][e][d], stride 40 (20 KB)
    __shared__ float km[8][32];
    __shared__ float zds[64][8];
    const int tid  = threadIdx.x;
    const int lane = tid & 63;
    const int wv   = tid >> 6;
    const int wvu  = __builtin_amdgcn_readfirstlane(wv);
    const int l15  = lane & 15;
    const int lq   = lane >> 4;
    const int b    = blockIdx.x >> 6;        // 64 blocks per batch
    const int n0   = (blockIdx.x & 63) * 64; // row base within batch
    const float inv_n = 1.0f / 4096.0f;

    // ---- Stage q rows via DMA (src pre-swizzled per row). -----------------
    {
        const int qr2 = lane >> 5;           // row within 2-row DMA group
        const int qc8 = (lane & 31) * 8;     // col (u16)
        const u16* qb = qy + (size_t)(b * 4096 + n0) * 256;
        #pragma unroll
        for (int it = 0; it < 8; ++it) {
            const int r = wvu * 16 + it * 2 + qr2;
            gl16(qb + (size_t)r * 256 + (qc8 ^ ((r & 7) << 3)),
                 &qs[(wvu * 16 + it * 2) * 256]);
        }
    }
    // ---- kvT + km staging. ------------------------------------------------
    {
        const int h = tid >> 5, e = tid & 31;
        const float* k0 = kvsum + (size_t)b * 8192 + h * 1024 + e;
        const float* k1 = kvsum + (size_t)(16 + b) * 8192 + h * 1024 + e;
        #pragma unroll
        for (int d = 0; d < 32; ++d)
            kvT[h * 1280 + e * 40 + d] = f2b((k0[d * 32] + k1[d * 32]) * inv_n);
        (&km[0][0])[tid] = (ksum[(size_t)b * 256 + tid] +
                            ksum[(size_t)(16 + b) * 256 + tid]) * inv_n;
    }
    __syncthreads();

    // ---- zd: once per (row, head); wave w handles heads 2w, 2w+1. ---------
    {
        const int zt = tid & 63;
        const int zh0 = (tid >> 6) * 2;
        #pragma unroll
        for (int hh = 0; hh < 2; ++hh) {
            const int h = zh0 + hh;
            float s = 0.f;
            #pragma unroll
            for (int d = 0; d < 32; ++d) {
                const int col = (h * 32 + d) ^ ((zt & 7) << 3);
                s = fmaf(b2f(qs[zt * 256 + col]), km[h][d], s);
            }
            zds[zt][h] = s;
        }
    }

    // ---- MFMA: wave rows [wvu*16, wvu*16+16), all 8 heads x 2 e-halves. ---
    f32x4 acc[8][2];
    #pragma unroll
    for (int h = 0; h < 8; ++h) {
        const int m = wvu * 16 + l15;
        const int col = (h * 32 + lq * 8) ^ ((m & 7) << 3);
        const short8 av = *reinterpret_cast<const short8*>(&qs[m * 256 + col]);
        const short8 b0 = *reinterpret_cast<const short8*>(
            &kvT[h * 1280 + l15 * 40 + lq * 8]);
        const short8 b1 = *reinterpret_cast<const short8*>(
            &kvT[h * 1280 + (16 + l15) * 40 + lq * 8]);
        const f32x4 z = {0.f, 0.f, 0.f, 0.f};
        acc[h][0] = __builtin_amdgcn_mfma_f32_16x16x32_bf16(av, b0, z, 0, 0, 0);
        acc[h][1] = __builtin_amdgcn_mfma_f32_16x16x32_bf16(av, b1, z, 0, 0, 0);
    }
    __syncthreads();

    // ---- Epilogue: divide by zd (broadcast read) and store. ---------------
    u16* qb = qy + (size_t)(b * 4096 + n0) * 256;
    #pragma unroll
    for (int h = 0; h < 8; ++h) {
        #pragma unroll
        for (int eh = 0; eh < 2; ++eh) {
            const int gcol = h * 32 + eh * 16 + l15;
            #pragma unroll
            for (int rg = 0; rg < 4; ++rg) {
                const int lr = wvu * 16 + lq * 4 + rg;
                const float z = 1.0f / (zds[lr][h] + 1e-6f);
                qb[(size_t)lr * 256 + gcol] = f2b(acc[h][eh][rg] * z);
            }
        }
    }
}

// ---------------------------------------------------------------------------
// Depthwise 5x5 conv: LDS-staged 12x12x256 halo tile, thread=channel,
// register sliding 5x12 window, 8x8 outputs/thread, += into y with bias.
// ---------------------------------------------------------------------------
__global__ __launch_bounds__(256, 2)
void conv_add_kernel(const u16* __restrict__ v, const void* __restrict__ w,
                     const void* __restrict__ bias, u16* __restrict__ y,
                     const int* __restrict__ flagp)
{
    const int f32 = *flagp;
    __shared__ u16 vt[144 * 256];   // [py*12+px][ch], 73728 B
    __shared__ float wl[800];
    __shared__ float bl[32];
    const int tid = threadIdx.x;
    for (int i = tid; i < 800; i += 256) wl[i] = ldv(w, i, f32);
    if (tid < 32) bl[tid] = ldv(bias, tid, f32);

    const int bb = blockIdx.x >> 6;
    const int ty = (blockIdx.x >> 3) & 7;
    const int tx = blockIdx.x & 7;
    const int y0 = ty * 8, x0 = tx * 8;
    const u16* vb = v + (size_t)bb * 4096 * 256;

    #pragma unroll
    for (int it = 0; it < 18; ++it) {
        const int idx = it * 256 + tid;       // 0..4607
        const int px  = idx >> 5;             // 0..143
        const int c8  = (idx & 31) * 8;
        const int py  = px / 12, pxx = px - py * 12;
        const int yy = y0 + py - 2, xx = x0 + pxx - 2;
        uint4 val = {0u, 0u, 0u, 0u};
        if (yy >= 0 && yy < 64 && xx >= 0 && xx < 64)
            val = *reinterpret_cast<const uint4*>(
                vb + (size_t)((yy << 6) + xx) * 256 + c8);
        *reinterpret_cast<uint4*>(&vt[px * 256 + c8]) = val;
    }
    __syncthreads();

    const int c  = tid;            // channel
    const int dc = c & 31;
    float wreg[25];
    #pragma unroll
    for (int i = 0; i < 25; ++i) wreg[i] = wl[dc * 25 + i];
    const float bv = bl[dc];

    float win[5][12];
    #pragma unroll
    for (int r = 0; r < 5; ++r)
        #pragma unroll
        for (int cc = 0; cc < 12; ++cc)
            win[r][cc] = b2f(vt[(r * 12 + cc) * 256 + c]);

    u16* yb = y + ((size_t)bb * 4096 + (size_t)y0 * 64 + x0) * 256 + c;
    #pragma unroll
    for (int oy = 0; oy < 8; ++oy) {
        if (oy) {
            #pragma unroll
            for (int r = 0; r < 4; ++r)
                #pragma unroll
                for (int cc = 0; cc < 12; ++cc) win[r][cc] = win[r + 1][cc];
            #pragma unroll
            for (int cc = 0; cc < 12; ++cc)
                win[4][cc] = b2f(vt[((oy + 4) * 12 + cc) * 256 + c]);
        }
        #pragma unroll
        for (int ox = 0; ox < 8; ++ox) {
            float s = 0.f;
            #pragma unroll
            for (int ky = 0; ky < 5; ++ky)
                #pragma unroll
                for (int kx = 0; kx < 5; ++kx)
                    s = fmaf(win[oy ? ky : ky][ox + kx], wreg[ky * 5 + kx], s);
            u16* yp = yb + (size_t)(oy * 64 + ox) * 256;
            *yp = f2b(b2f(*yp) + s + bv);
        }
    }
}

// ---------------------------------------------------------------------------
extern "C" void kernel_launch(void* const* d_in, const int* in_sizes, int n_in,
                              void* d_out, int out_size, void* d_ws, size_t ws_size,
                              hipStream_t stream)
{
    (void)in_sizes; (void)n_in; (void)out_size;
    const void* x   = d_in[0];
    const void* Wq  = d_in[1];
    const void* Wkv = d_in[2];
    const void* Wp  = d_in[3];
    const void* bp  = d_in[4];
    const void* sp  = d_in[5];
    const void* pe  = d_in[6];
    const void* dw  = d_in[7];
    const void* db  = d_in[8];

    // ws layout:
    // [flag 64B][kvsm 1M (2 slots)][ksm 32K (2 slots)][WqT 128K][WkvT 256K]
    // [WpT 128K][peb 2M][qy 32M][xb 32M (only if ws large enough)]
    int*   flag = (int*)d_ws;
    float* kvsm = (float*)((char*)d_ws + 64);
    float* ksm  = kvsm + 262144;
    u16*   WqT  = (u16*)(ksm + 8192);
    u16*   WkvT = WqT + 65536;
    u16*   WpT  = WkvT + 131072;
    u16*   peb  = WpT + 65536;
    u16*   qy   = peb + 1048576;
    u16*   xb   = qy + (size_t)16777216;
    // v (bf16, 33.5 MB) parked at the START of d_out (dead before the final
    // GEMM overwrites d_out).
    u16*   v    = (u16*)d_out;

    const size_t need = (size_t)((char*)(xb + 16777216) - (char*)d_ws);
    const int big = (ws_size >= need) ? 1 : 0;

    hipMemsetAsync(kvsm, 0, (262144 + 8192) * sizeof(float), stream);
    detect_kernel<<<1, 64, 0, stream>>>(x, flag);
    if (big) xcvt_kernel<<<8192, 256, 0, stream>>>(x, xb, flag);
    prep_kernel<<<1280, 256, 0, stream>>>(pe, peb, Wq, WqT, Wkv, WkvT,
                                          Wp, WpT, flag);

    const void* Ax = big ? (const void*)xb : x;

    // q = focus(x @ Wq)
    hipLaunchKernelGGL((gemm256<3>), dim3(512), dim3(256), 0, stream,
                       Ax, (const u16*)nullptr, WqT, qy, sp, flag, big);
    // v = x @ Wkv[:, 256:]
    hipLaunchKernelGGL((gemm256<0>), dim3(512), dim3(256), 0, stream,
                       Ax, (const u16*)nullptr, WkvT + (size_t)256 * 256, v,
                       (const void*)nullptr, flag, big);
    // fused k path: gemm + pe + focus + kvsum/ksum (k never materialized)
    fusedk_kernel<<<512, 256, 0, stream>>>(Ax, WkvT, peb, v, sp, kvsm, ksm,
                                           flag, big);

    attn_mfma_kernel<<<1024, 256, 0, stream>>>(qy, kvsm, ksm);
    conv_add_kernel<<<1024, 256, 0, stream>>>(v, dw, db, qy, flag);
    hipLaunchKernelGGL((gemm256<2>), dim3(512), dim3(256), 0, stream,
                       (const void*)nullptr, qy, WpT, (u16*)d_out, bp, flag, 0);
}